// Round 5
// baseline (925.491 us; speedup 1.0000x reference)
//
#include <hip/hip_runtime.h>

typedef __attribute__((ext_vector_type(8))) short bf16x8;
typedef __attribute__((ext_vector_type(4))) float f32x4;

#define MFMA16(a, b, c) __builtin_amdgcn_mfma_f32_16x16x32_bf16((a), (b), (c), 0, 0, 0)

__device__ __forceinline__ float b2f(unsigned short u) {
  unsigned int v = ((unsigned int)u) << 16;
  return __builtin_bit_cast(float, v);
}
__device__ __forceinline__ unsigned short f2b(float f) {
  unsigned int u = __builtin_bit_cast(unsigned int, f);
  u += 0x7fffu + ((u >> 16) & 1u);
  return (unsigned short)(u >> 16);
}
__device__ __forceinline__ void gload16(const void* g, void* l) {
  __builtin_amdgcn_global_load_lds(
      (const __attribute__((address_space(1))) unsigned int*)g,
      (__attribute__((address_space(3))) unsigned int*)l, 16, 0, 0);
}

// ---------------- K-1: weights fp32 -> bf16, layout preserved [o][c] ----------------
__global__ __launch_bounds__(256) void k_wconv(
    const float* __restrict__ w0, const float* __restrict__ w1,
    const float* __restrict__ w2, const float* __restrict__ w3,
    unsigned short* __restrict__ out) {
  const float* src = (blockIdx.y == 0) ? w0 : (blockIdx.y == 1) ? w1
                     : (blockIdx.y == 2) ? w2 : w3;
  unsigned short* dst = out + (size_t)blockIdx.y * 262144u;
  const int i = (blockIdx.x * 256 + threadIdx.x) * 4;
  const float4 v = *(const float4*)(src + i);
  uint2 p;
  p.x = (unsigned int)f2b(v.x) | ((unsigned int)f2b(v.y) << 16);
  p.y = (unsigned int)f2b(v.z) | ((unsigned int)f2b(v.w) << 16);
  *(uint2*)(dst + i) = p;
}

// ---------------- K0: x fp32 [b][c][p] -> xT bf16 [b*16384+p][c] ----------------
__global__ __launch_bounds__(256) void k_transpose(
    const float* __restrict__ X, unsigned short* __restrict__ XT) {
  __shared__ unsigned short tile[64][72];
  const int p0 = blockIdx.x << 6, c0 = blockIdx.y << 6, b = blockIdx.z;
  const float* xb = X + (size_t)b * 8388608u;
  unsigned short* xtb = XT + (size_t)b * 8388608u;
  const int t = threadIdx.x;
  {
    const int cl = t >> 3, pl = (t & 7) << 3;
#pragma unroll
    for (int pass = 0; pass < 2; ++pass) {
      const int c = cl + pass * 32;
      const float* src = xb + (size_t)(c0 + c) * 16384 + p0 + pl;
      const float4 f0 = ((const float4*)src)[0];
      const float4 f1 = ((const float4*)src)[1];
      tile[pl + 0][c] = f2b(f0.x);
      tile[pl + 1][c] = f2b(f0.y);
      tile[pl + 2][c] = f2b(f0.z);
      tile[pl + 3][c] = f2b(f0.w);
      tile[pl + 4][c] = f2b(f1.x);
      tile[pl + 5][c] = f2b(f1.y);
      tile[pl + 6][c] = f2b(f1.z);
      tile[pl + 7][c] = f2b(f1.w);
    }
  }
  __syncthreads();
  {
    const int pl = t >> 3, cl = (t & 7) << 3;
#pragma unroll
    for (int pass = 0; pass < 2; ++pass) {
      const int p = pl + pass * 32;
      uint4 v = *(const uint4*)&tile[p][cl];
      *(uint4*)(xtb + (size_t)(p0 + p) * 512 + c0 + cl) = v;
    }
  }
}

// ---------------- fused Q+K projection ----------------
// grid 8192 (1-D). XCD-chunked: work = (bid&7)*1024 + bid>>3; ny = work&7 fastest
// -> 8 consecutive works (2 matrices x 4 n-tiles) share one A-tile on one XCD.
__global__ __launch_bounds__(256) void k_gemm_qk(
    const unsigned short* __restrict__ A, const unsigned short* __restrict__ W,
    const float* __restrict__ bqp, const float* __restrict__ bkp,
    unsigned short* __restrict__ Cq, unsigned short* __restrict__ Ck) {
  __shared__ unsigned short lsA[128 * 64];
  __shared__ unsigned short lsB[128 * 64];
  const int bid = blockIdx.x;
  const int work = ((bid & 7) << 10) + (bid >> 3);
  const int mt = work >> 3, ny = work & 7;
  const int mat = ny >> 2, nt = ny & 3;
  const unsigned short* B = W + mat * 262144;
  const float* bias = mat ? bkp : bqp;
  unsigned short* C = mat ? Ck : Cq;
  const int m0 = mt << 7, n0 = nt << 7;

  const int t = threadIdx.x;
  const int w = t >> 6, l = t & 63;
  const int lr = l & 15, lg = l >> 4;
  const int srow = (w << 5) + (l >> 3);
  const int skk = (l & 7) << 3;
  const int ra = ((w >> 1) << 6), rb = ((w & 1) << 6);

  f32x4 acc[4][4];
#pragma unroll
  for (int i = 0; i < 4; ++i)
#pragma unroll
    for (int j = 0; j < 4; ++j) acc[i][j] = f32x4{0.f, 0.f, 0.f, 0.f};

  for (int kt = 0; kt < 8; ++kt) {
    const int k0 = kt << 6;
    __syncthreads();
#pragma unroll
    for (int i = 0; i < 4; ++i) {
      gload16(A + (size_t)(m0 + srow + i * 8) * 512 + k0 + skk,
              lsA + ((w << 5) + i * 8) * 64);
      gload16(B + (size_t)(n0 + srow + i * 8) * 512 + k0 + skk,
              lsB + ((w << 5) + i * 8) * 64);
    }
    __syncthreads();
#pragma unroll
    for (int kk = 0; kk < 2; ++kk) {
      bf16x8 af[4], bfv[4];
#pragma unroll
      for (int i = 0; i < 4; ++i)
        af[i] = *(const bf16x8*)&lsA[(ra + i * 16 + lr) * 64 + kk * 32 + lg * 8];
#pragma unroll
      for (int j = 0; j < 4; ++j)
        bfv[j] = *(const bf16x8*)&lsB[(rb + j * 16 + lr) * 64 + kk * 32 + lg * 8];
#pragma unroll
      for (int i = 0; i < 4; ++i)
#pragma unroll
        for (int j = 0; j < 4; ++j)
          acc[i][j] = MFMA16(af[i], bfv[j], acc[i][j]);
    }
  }

#pragma unroll
  for (int i = 0; i < 4; ++i) {
    const int cmb = m0 + ra + i * 16 + lg * 4;
#pragma unroll
    for (int j = 0; j < 4; ++j) {
      const int cn = n0 + rb + j * 16 + lr;
      const float bn = bias[cn];
#pragma unroll
      for (int r = 0; r < 4; ++r) {
        const int cm = cmb + r;
        C[(size_t)cm * 512 + cn] = f2b(acc[i][j][r] + bn);
      }
    }
  }
}

// ---------------- GEMM: C[m][n] = sum_k A[m][k]*B[n][k] + bias[m], K=512 ----------------
// grid 4096 (1-D), XCD-chunked; 4 consecutive works (mt=0..3) share a B-tile.
// MODE 1: bf16 C[m=chan][n=pixel], ldc=131072    (V projection)
// MODE 2: fp32 C -> (B,C,H,W) from [m=chan][n=pixel]  (O projection)
template <int MODE>
__global__ __launch_bounds__(256) void k_gemm(
    const unsigned short* __restrict__ A, const unsigned short* __restrict__ B,
    const float* __restrict__ bias, void* __restrict__ Cv) {
  __shared__ unsigned short lsA[128 * 64];
  __shared__ unsigned short lsB[128 * 64];
  const int bid = blockIdx.x;
  const int work = ((bid & 7) << 9) + (bid >> 3);
  const int nt = work >> 2, mt = work & 3;
  const int m0 = mt << 7, n0 = nt << 7;

  const int t = threadIdx.x;
  const int w = t >> 6, l = t & 63;
  const int lr = l & 15, lg = l >> 4;
  const int srow = (w << 5) + (l >> 3);
  const int skk = (l & 7) << 3;
  const int ra = ((w >> 1) << 6), rb = ((w & 1) << 6);

  f32x4 acc[4][4];
#pragma unroll
  for (int i = 0; i < 4; ++i)
#pragma unroll
    for (int j = 0; j < 4; ++j) acc[i][j] = f32x4{0.f, 0.f, 0.f, 0.f};

  for (int kt = 0; kt < 8; ++kt) {
    const int k0 = kt << 6;
    __syncthreads();
#pragma unroll
    for (int i = 0; i < 4; ++i) {
      gload16(A + (size_t)(m0 + srow + i * 8) * 512 + k0 + skk,
              lsA + ((w << 5) + i * 8) * 64);
      gload16(B + (size_t)(n0 + srow + i * 8) * 512 + k0 + skk,
              lsB + ((w << 5) + i * 8) * 64);
    }
    __syncthreads();
#pragma unroll
    for (int kk = 0; kk < 2; ++kk) {
      bf16x8 af[4], bfv[4];
#pragma unroll
      for (int i = 0; i < 4; ++i)
        af[i] = *(const bf16x8*)&lsA[(ra + i * 16 + lr) * 64 + kk * 32 + lg * 8];
#pragma unroll
      for (int j = 0; j < 4; ++j)
        bfv[j] = *(const bf16x8*)&lsB[(rb + j * 16 + lr) * 64 + kk * 32 + lg * 8];
#pragma unroll
      for (int i = 0; i < 4; ++i)
#pragma unroll
        for (int j = 0; j < 4; ++j)
          acc[i][j] = MFMA16(af[i], bfv[j], acc[i][j]);
    }
  }

  unsigned short* Cs = (unsigned short*)Cv;
  float* Cf = (float*)Cv;
#pragma unroll
  for (int i = 0; i < 4; ++i) {
    const int cmb = m0 + ra + i * 16 + lg * 4;
#pragma unroll
    for (int j = 0; j < 4; ++j) {
      const int cn = n0 + rb + j * 16 + lr;
#pragma unroll
      for (int r = 0; r < 4; ++r) {
        const int cm = cmb + r;
        const float val = acc[i][j][r] + bias[cm];
        if (MODE == 1) {
          Cs[(size_t)cm * 131072 + cn] = f2b(val);
        } else {
          const int bb = cn >> 14, p = cn & 16383;
          Cf[(size_t)bb * 8388608 + (size_t)cm * 16384 + p] = val;  // fp32 out
        }
      }
    }
  }
}

// ---------------- K2: window attention (MFMA) ----------------
// Q,K: [pixel][c] bf16.  V: [c][pixel] bf16.  AO out: [pixel][c] bf16.
// XCD-chunked win swizzle: each XCD owns 256 consecutive windows so
// tw-adjacent windows (sharing V cache lines) hit the same L2.
__global__ __launch_bounds__(256) void k_attn(
    const unsigned short* __restrict__ Q, const unsigned short* __restrict__ K,
    const unsigned short* __restrict__ V, unsigned short* __restrict__ AO) {
  __shared__ unsigned short P_lds[64][72];
  const int win = ((blockIdx.x & 7) << 8) + (blockIdx.x >> 3);
  const int b = win >> 8, th = (win >> 4) & 15, tw = win & 15;
  const size_t p_base = (size_t)b * 16384 + (size_t)th * 1024 + (size_t)tw * 8;
  const int t = threadIdx.x, w = t >> 6, l = t & 63;
  const int lr = l & 15, lg = l >> 4;
  const int qs = w << 4;
  const int qtok = qs + lr;
  const unsigned short* qrow =
      Q + (p_base + (size_t)(qtok >> 3) * 128 + (qtok & 7)) * 512;
  const unsigned short* krow =
      K + (p_base + (size_t)(lr >> 3) * 128 + (lr & 7)) * 512;

  // S'[k_tok][q] = mfma(A=K, B=Q): lane holds q=lr, k = mt*16 + lg*4 + j
  f32x4 acc[4];
#pragma unroll
  for (int i = 0; i < 4; ++i) acc[i] = f32x4{0.f, 0.f, 0.f, 0.f};

  for (int cs = 0; cs < 16; ++cs) {
    const int co = cs * 32 + lg * 8;
    const bf16x8 bq = *(const bf16x8*)(qrow + co);
#pragma unroll
    for (int mt = 0; mt < 4; ++mt) {
      const bf16x8 ak = *(const bf16x8*)(krow + (size_t)mt * 131072 + co);
      acc[mt] = MFMA16(ak, bq, acc[mt]);
    }
  }

  const float scale = 0.044194173824159216f;  // 1/sqrt(512)
  float pv[4][4];
  float mx = -3.0e38f;
#pragma unroll
  for (int mt = 0; mt < 4; ++mt)
#pragma unroll
    for (int j = 0; j < 4; ++j) {
      const float s = acc[mt][j] * scale;
      pv[mt][j] = s;
      mx = fmaxf(mx, s);
    }
  mx = fmaxf(mx, __shfl_xor(mx, 16));
  mx = fmaxf(mx, __shfl_xor(mx, 32));
  float sum = 0.f;
#pragma unroll
  for (int mt = 0; mt < 4; ++mt)
#pragma unroll
    for (int j = 0; j < 4; ++j) {
      const float e = __expf(pv[mt][j] - mx);
      pv[mt][j] = e;
      sum += e;
    }
  sum += __shfl_xor(sum, 16);
  sum += __shfl_xor(sum, 32);
  const float inv = 1.f / sum;

  // P[q][k] -> LDS (bf16, padded pitch 72)
#pragma unroll
  for (int mt = 0; mt < 4; ++mt)
#pragma unroll
    for (int j = 0; j < 4; j += 2) {
      const unsigned int pk =
          (unsigned int)f2b(pv[mt][j] * inv) |
          ((unsigned int)f2b(pv[mt][j + 1] * inv) << 16);
      *(unsigned int*)&P_lds[qtok][mt * 16 + lg * 4 + j] = pk;
    }
  __syncthreads();

  // PV: O[q][c] = mfma(A=P[q][tok], B=V[tok][c])
  const bf16x8 pa0 = *(const bf16x8*)&P_lds[qtok][lg * 8];
  const bf16x8 pa1 = *(const bf16x8*)&P_lds[qtok][32 + lg * 8];
  const unsigned short* vbase =
      V + (size_t)lr * 131072 + p_base + (size_t)lg * 128;
  for (int nt = 0; nt < 32; ++nt) {
    const unsigned short* vp = vbase + (size_t)nt * (16 * 131072);
    const bf16x8 v0 = *(const bf16x8*)vp;
    const bf16x8 v1 = *(const bf16x8*)(vp + 512);
    f32x4 o = f32x4{0.f, 0.f, 0.f, 0.f};
    o = MFMA16(pa0, v0, o);
    o = MFMA16(pa1, v1, o);
#pragma unroll
    for (int r = 0; r < 4; ++r) {
      const int qq = qs + lg * 4 + r;
      const size_t p = p_base + (size_t)(qq >> 3) * 128 + (qq & 7);
      AO[p * 512 + nt * 16 + lr] = f2b(o[r]);
    }
  }
}

// ---------------- launch ----------------
extern "C" void kernel_launch(void* const* d_in, const int* in_sizes, int n_in,
                              void* d_out, int out_size, void* d_ws,
                              size_t ws_size, hipStream_t stream) {
  (void)in_sizes; (void)n_in; (void)out_size;
  const float* x = (const float*)d_in[0];
  const float* wq = (const float*)d_in[1];
  const float* bq = (const float*)d_in[2];
  const float* wk = (const float*)d_in[3];
  const float* bk = (const float*)d_in[4];
  const float* wv = (const float*)d_in[5];
  const float* bv = (const float*)d_in[6];
  const float* wo = (const float*)d_in[7];
  const float* bo = (const float*)d_in[8];

  // layout: wb (2M shorts) | xT (64M) | K (64M) | V (64M)
  const size_t NEED = (size_t)(2097152 + 3 * 67108864) * 2;
  if (ws_size < NEED) return;

  unsigned short* wb = (unsigned short*)d_ws;
  unsigned short* xT = wb + 2097152;    // [pixel][c]; reused as AO
  unsigned short* kws = xT + 67108864;  // k: [pixel][c]
  unsigned short* vws = kws + 67108864; // v: [c][pixel]
  unsigned short* qws = (unsigned short*)d_out;  // q staged (bf16), fully
                                                 // overwritten by MODE 2 fp32

  k_wconv<<<dim3(256, 4), 256, 0, stream>>>(wq, wk, wv, wo, wb);
  k_transpose<<<dim3(256, 8, 8), 256, 0, stream>>>(x, xT);
  k_gemm_qk<<<8192, 256, 0, stream>>>(xT, wb, bq, bk, qws, kws);
  k_gemm<1><<<4096, 256, 0, stream>>>(wb + 524288, xT, bv, vws);
  k_attn<<<2048, 256, 0, stream>>>(qws, kws, vws, xT);
  k_gemm<2><<<4096, 256, 0, stream>>>(wb + 786432, xT, bo, d_out);
}

// Round 6
// 888.354 us; speedup vs baseline: 1.0418x; 1.0418x over previous
//
#include <hip/hip_runtime.h>

typedef __attribute__((ext_vector_type(8))) short bf16x8;
typedef __attribute__((ext_vector_type(4))) float f32x4;

#define MFMA16(a, b, c) __builtin_amdgcn_mfma_f32_16x16x32_bf16((a), (b), (c), 0, 0, 0)

__device__ __forceinline__ float b2f(unsigned short u) {
  unsigned int v = ((unsigned int)u) << 16;
  return __builtin_bit_cast(float, v);
}
__device__ __forceinline__ unsigned short f2b(float f) {
  unsigned int u = __builtin_bit_cast(unsigned int, f);
  u += 0x7fffu + ((u >> 16) & 1u);
  return (unsigned short)(u >> 16);
}
__device__ __forceinline__ void gload16(const void* g, void* l) {
  __builtin_amdgcn_global_load_lds(
      (const __attribute__((address_space(1))) unsigned int*)g,
      (__attribute__((address_space(3))) unsigned int*)l, 16, 0, 0);
}

// ---------------- weights fp32 -> bf16, layout preserved [o][c] ----------------
// blockIdx.y: 0 -> wq @0, 1 -> wk @262144, 2 -> wo @786432
__global__ __launch_bounds__(256) void k_wconv(
    const float* __restrict__ w0, const float* __restrict__ w1,
    const float* __restrict__ w2, unsigned short* __restrict__ out) {
  const float* src = (blockIdx.y == 0) ? w0 : (blockIdx.y == 1) ? w1 : w2;
  unsigned short* dst =
      out + (size_t)((blockIdx.y == 0) ? 0 : (blockIdx.y == 1) ? 262144 : 786432);
  const int i = (blockIdx.x * 256 + threadIdx.x) * 4;
  const float4 v = *(const float4*)(src + i);
  uint2 p;
  p.x = (unsigned int)f2b(v.x) | ((unsigned int)f2b(v.y) << 16);
  p.y = (unsigned int)f2b(v.z) | ((unsigned int)f2b(v.w) << 16);
  *(uint2*)(dst + i) = p;
}

// ---------------- wv fp32 [cv][j] -> wvT bf16 [j][cv] ----------------
__global__ __launch_bounds__(256) void k_wtrans(
    const float* __restrict__ in, unsigned short* __restrict__ out) {
  __shared__ unsigned short tile[64][72];
  const int r0 = blockIdx.x << 6, s0 = blockIdx.y << 6;  // r=j, s=cv
  const int t = threadIdx.x;
  {
    const int sl = t >> 3, rl = (t & 7) << 3;
#pragma unroll
    for (int pass = 0; pass < 2; ++pass) {
      const int s = sl + pass * 32;
      const float* src = in + (size_t)(s0 + s) * 512 + r0 + rl;
      const float4 f0 = ((const float4*)src)[0];
      const float4 f1 = ((const float4*)src)[1];
      tile[rl + 0][s] = f2b(f0.x);
      tile[rl + 1][s] = f2b(f0.y);
      tile[rl + 2][s] = f2b(f0.z);
      tile[rl + 3][s] = f2b(f0.w);
      tile[rl + 4][s] = f2b(f1.x);
      tile[rl + 5][s] = f2b(f1.y);
      tile[rl + 6][s] = f2b(f1.z);
      tile[rl + 7][s] = f2b(f1.w);
    }
  }
  __syncthreads();
  {
    const int rl = t >> 3, sl = (t & 7) << 3;
#pragma unroll
    for (int pass = 0; pass < 2; ++pass) {
      const int r = rl + pass * 32;
      uint4 v = *(const uint4*)&tile[r][sl];
      *(uint4*)(out + (size_t)(r0 + r) * 512 + s0 + sl) = v;
    }
  }
}

// ---------------- bvo[o] = bo[o] + sum_j wo[o][j]*bv[j]  (fp32) ----------------
__global__ __launch_bounds__(256) void k_bvo(
    const float* __restrict__ wo, const float* __restrict__ bv,
    const float* __restrict__ bo, float* __restrict__ bvo) {
  const int o = blockIdx.x * 256 + threadIdx.x;
  float acc = bo[o];
  const float* row = wo + (size_t)o * 512;
  for (int j = 0; j < 512; ++j) acc += row[j] * bv[j];
  bvo[o] = acc;
}

// ---------- K0: x fp32 [b][c][p] -> xT bf16 [pixel][c]  AND  xV bf16 [c][win*64+tok] ----------
__global__ __launch_bounds__(256) void k_transpose(
    const float* __restrict__ X, unsigned short* __restrict__ XT,
    unsigned short* __restrict__ XV) {
  __shared__ unsigned short tile[64][72];
  const int p0 = blockIdx.x << 6, c0 = blockIdx.y << 6, b = blockIdx.z;
  const float* xb = X + (size_t)b * 8388608u;
  unsigned short* xtb = XT + (size_t)b * 8388608u;
  const int t = threadIdx.x;
  const int h = p0 >> 7, th2 = h >> 3, hrow = h & 7;
  const int widb = b * 256 + th2 * 16 + ((p0 & 127) >> 3);
  {
    const int cl = t >> 3, pl = (t & 7) << 3;
    const int widx = t & 7;
#pragma unroll
    for (int pass = 0; pass < 2; ++pass) {
      const int c = cl + pass * 32;
      const float* src = xb + (size_t)(c0 + c) * 16384 + p0 + pl;
      const float4 f0 = ((const float4*)src)[0];
      const float4 f1 = ((const float4*)src)[1];
      unsigned short r8[8];
      r8[0] = f2b(f0.x); r8[1] = f2b(f0.y); r8[2] = f2b(f0.z); r8[3] = f2b(f0.w);
      r8[4] = f2b(f1.x); r8[5] = f2b(f1.y); r8[6] = f2b(f1.z); r8[7] = f2b(f1.w);
#pragma unroll
      for (int i = 0; i < 8; ++i) tile[pl + i][c] = r8[i];
      // window-contiguous copy: these 8 pixels are one window-row (hrow) of
      // window widb+widx in channel c0+c.
      *(uint4*)(XV + (size_t)(c0 + c) * 131072 +
                (size_t)(widb + widx) * 64 + hrow * 8) = *(const uint4*)r8;
    }
  }
  __syncthreads();
  {
    const int pl = t >> 3, cl = (t & 7) << 3;
#pragma unroll
    for (int pass = 0; pass < 2; ++pass) {
      const int p = pl + pass * 32;
      uint4 v = *(const uint4*)&tile[p][cl];
      *(uint4*)(xtb + (size_t)(p0 + p) * 512 + c0 + cl) = v;
    }
  }
}

// ---------------- fused Q+K projection ----------------
// grid 8192 (1-D). XCD-chunked: work = (bid&7)*1024 + bid>>3; ny = work&7 fastest
// -> 8 consecutive works (2 matrices x 4 n-tiles) share one A-tile on one XCD.
__global__ __launch_bounds__(256) void k_gemm_qk(
    const unsigned short* __restrict__ A, const unsigned short* __restrict__ W,
    const float* __restrict__ bqp, const float* __restrict__ bkp,
    unsigned short* __restrict__ Cq, unsigned short* __restrict__ Ck) {
  __shared__ unsigned short lsA[128 * 64];
  __shared__ unsigned short lsB[128 * 64];
  const int bid = blockIdx.x;
  const int work = ((bid & 7) << 10) + (bid >> 3);
  const int mt = work >> 3, ny = work & 7;
  const int mat = ny >> 2, nt = ny & 3;
  const unsigned short* B = W + mat * 262144;
  const float* bias = mat ? bkp : bqp;
  unsigned short* C = mat ? Ck : Cq;
  const int m0 = mt << 7, n0 = nt << 7;

  const int t = threadIdx.x;
  const int w = t >> 6, l = t & 63;
  const int lr = l & 15, lg = l >> 4;
  const int srow = (w << 5) + (l >> 3);
  const int skk = (l & 7) << 3;
  const int ra = ((w >> 1) << 6), rb = ((w & 1) << 6);

  f32x4 acc[4][4];
#pragma unroll
  for (int i = 0; i < 4; ++i)
#pragma unroll
    for (int j = 0; j < 4; ++j) acc[i][j] = f32x4{0.f, 0.f, 0.f, 0.f};

  for (int kt = 0; kt < 8; ++kt) {
    const int k0 = kt << 6;
    __syncthreads();
#pragma unroll
    for (int i = 0; i < 4; ++i) {
      gload16(A + (size_t)(m0 + srow + i * 8) * 512 + k0 + skk,
              lsA + ((w << 5) + i * 8) * 64);
      gload16(B + (size_t)(n0 + srow + i * 8) * 512 + k0 + skk,
              lsB + ((w << 5) + i * 8) * 64);
    }
    __syncthreads();
#pragma unroll
    for (int kk = 0; kk < 2; ++kk) {
      bf16x8 af[4], bfv[4];
#pragma unroll
      for (int i = 0; i < 4; ++i)
        af[i] = *(const bf16x8*)&lsA[(ra + i * 16 + lr) * 64 + kk * 32 + lg * 8];
#pragma unroll
      for (int j = 0; j < 4; ++j)
        bfv[j] = *(const bf16x8*)&lsB[(rb + j * 16 + lr) * 64 + kk * 32 + lg * 8];
#pragma unroll
      for (int i = 0; i < 4; ++i)
#pragma unroll
        for (int j = 0; j < 4; ++j)
          acc[i][j] = MFMA16(af[i], bfv[j], acc[i][j]);
    }
  }

#pragma unroll
  for (int i = 0; i < 4; ++i) {
    const int cmb = m0 + ra + i * 16 + lg * 4;
#pragma unroll
    for (int j = 0; j < 4; ++j) {
      const int cn = n0 + rb + j * 16 + lr;
      const float bn = bias[cn];
#pragma unroll
      for (int r = 0; r < 4; ++r) {
        const int cm = cmb + r;
        C[(size_t)cm * 512 + cn] = f2b(acc[i][j][r] + bn);
      }
    }
  }
}

// ---------------- GEMM: C[m][n] = sum_k A[m][k]*B[n][k], K=512 ----------------
// MODE 2: fp32 C -> (B,C,H,W) from [m=chan][n=pixel], +bias[m]  (final out)
//         grid 4096 1-D XCD-chunked.
// MODE 3: bf16 C[m][n] ldc=512, no bias (Wvo precompute), grid 16.
template <int MODE>
__global__ __launch_bounds__(256) void k_gemm(
    const unsigned short* __restrict__ A, const unsigned short* __restrict__ B,
    const float* __restrict__ bias, void* __restrict__ Cv) {
  __shared__ unsigned short lsA[128 * 64];
  __shared__ unsigned short lsB[128 * 64];
  const int bid = blockIdx.x;
  int mt, nt;
  if (MODE == 3) {
    mt = bid & 3; nt = bid >> 2;
  } else {
    const int work = ((bid & 7) << 9) + (bid >> 3);
    nt = work >> 2; mt = work & 3;
  }
  const int m0 = mt << 7, n0 = nt << 7;

  const int t = threadIdx.x;
  const int w = t >> 6, l = t & 63;
  const int lr = l & 15, lg = l >> 4;
  const int srow = (w << 5) + (l >> 3);
  const int skk = (l & 7) << 3;
  const int ra = ((w >> 1) << 6), rb = ((w & 1) << 6);

  f32x4 acc[4][4];
#pragma unroll
  for (int i = 0; i < 4; ++i)
#pragma unroll
    for (int j = 0; j < 4; ++j) acc[i][j] = f32x4{0.f, 0.f, 0.f, 0.f};

  for (int kt = 0; kt < 8; ++kt) {
    const int k0 = kt << 6;
    __syncthreads();
#pragma unroll
    for (int i = 0; i < 4; ++i) {
      gload16(A + (size_t)(m0 + srow + i * 8) * 512 + k0 + skk,
              lsA + ((w << 5) + i * 8) * 64);
      gload16(B + (size_t)(n0 + srow + i * 8) * 512 + k0 + skk,
              lsB + ((w << 5) + i * 8) * 64);
    }
    __syncthreads();
#pragma unroll
    for (int kk = 0; kk < 2; ++kk) {
      bf16x8 af[4], bfv[4];
#pragma unroll
      for (int i = 0; i < 4; ++i)
        af[i] = *(const bf16x8*)&lsA[(ra + i * 16 + lr) * 64 + kk * 32 + lg * 8];
#pragma unroll
      for (int j = 0; j < 4; ++j)
        bfv[j] = *(const bf16x8*)&lsB[(rb + j * 16 + lr) * 64 + kk * 32 + lg * 8];
#pragma unroll
      for (int i = 0; i < 4; ++i)
#pragma unroll
        for (int j = 0; j < 4; ++j)
          acc[i][j] = MFMA16(af[i], bfv[j], acc[i][j]);
    }
  }

  unsigned short* Cs = (unsigned short*)Cv;
  float* Cf = (float*)Cv;
#pragma unroll
  for (int i = 0; i < 4; ++i) {
    const int cmb = m0 + ra + i * 16 + lg * 4;
#pragma unroll
    for (int j = 0; j < 4; ++j) {
      const int cn = n0 + rb + j * 16 + lr;
#pragma unroll
      for (int r = 0; r < 4; ++r) {
        const int cm = cmb + r;
        if (MODE == 3) {
          Cs[(size_t)cm * 512 + cn] = f2b(acc[i][j][r]);
        } else {
          const float val = acc[i][j][r] + bias[cm];
          const int bb = cn >> 14, p = cn & 16383;
          Cf[(size_t)bb * 8388608 + (size_t)cm * 16384 + p] = val;  // fp32 out
        }
      }
    }
  }
}

// ---------------- K2: window attention + PV against raw x ----------------
// Q,K: [pixel][c] bf16.  XV: [c][win*64+tok] bf16.  Y out -> K buffer (in-place,
// window-private rows), layout [pixel][c] bf16.
__global__ __launch_bounds__(256) void k_attn(
    const unsigned short* __restrict__ Q, const unsigned short* __restrict__ K,
    const unsigned short* __restrict__ XV, unsigned short* __restrict__ Y) {
  __shared__ unsigned short P_lds[64][72];
  const int win = ((blockIdx.x & 7) << 8) + (blockIdx.x >> 3);
  const int b = win >> 8, th = (win >> 4) & 15, tw = win & 15;
  const size_t p_base = (size_t)b * 16384 + (size_t)th * 1024 + (size_t)tw * 8;
  const int t = threadIdx.x, w = t >> 6, l = t & 63;
  const int lr = l & 15, lg = l >> 4;
  const int qs = w << 4;
  const int qtok = qs + lr;
  const unsigned short* qrow =
      Q + (p_base + (size_t)(qtok >> 3) * 128 + (qtok & 7)) * 512;
  const unsigned short* krow =
      K + (p_base + (size_t)(lr >> 3) * 128 + (lr & 7)) * 512;

  // S'[k_tok][q] = mfma(A=K, B=Q): lane holds q=lr, k = mt*16 + lg*4 + j
  f32x4 acc[4];
#pragma unroll
  for (int i = 0; i < 4; ++i) acc[i] = f32x4{0.f, 0.f, 0.f, 0.f};

  for (int cs = 0; cs < 16; ++cs) {
    const int co = cs * 32 + lg * 8;
    const bf16x8 bq = *(const bf16x8*)(qrow + co);
#pragma unroll
    for (int mt = 0; mt < 4; ++mt) {
      const bf16x8 ak = *(const bf16x8*)(krow + (size_t)mt * 131072 + co);
      acc[mt] = MFMA16(ak, bq, acc[mt]);
    }
  }

  const float scale = 0.044194173824159216f;  // 1/sqrt(512)
  float pv[4][4];
  float mx = -3.0e38f;
#pragma unroll
  for (int mt = 0; mt < 4; ++mt)
#pragma unroll
    for (int j = 0; j < 4; ++j) {
      const float s = acc[mt][j] * scale;
      pv[mt][j] = s;
      mx = fmaxf(mx, s);
    }
  mx = fmaxf(mx, __shfl_xor(mx, 16));
  mx = fmaxf(mx, __shfl_xor(mx, 32));
  float sum = 0.f;
#pragma unroll
  for (int mt = 0; mt < 4; ++mt)
#pragma unroll
    for (int j = 0; j < 4; ++j) {
      const float e = __expf(pv[mt][j] - mx);
      pv[mt][j] = e;
      sum += e;
    }
  sum += __shfl_xor(sum, 16);
  sum += __shfl_xor(sum, 32);
  const float inv = 1.f / sum;

  // P[q][k] -> LDS (bf16, padded pitch 72)
#pragma unroll
  for (int mt = 0; mt < 4; ++mt)
#pragma unroll
    for (int j = 0; j < 4; j += 2) {
      const unsigned int pk =
          (unsigned int)f2b(pv[mt][j] * inv) |
          ((unsigned int)f2b(pv[mt][j + 1] * inv) << 16);
      *(unsigned int*)&P_lds[qtok][mt * 16 + lg * 4 + j] = pk;
    }
  __syncthreads();

  // PV: Y[q][c] = mfma(A=P[q][tok], B=X[tok][c]) from window-contiguous XV
  const bf16x8 pa0 = *(const bf16x8*)&P_lds[qtok][lg * 8];
  const bf16x8 pa1 = *(const bf16x8*)&P_lds[qtok][32 + lg * 8];
  const unsigned short* vbase =
      XV + (size_t)lr * 131072 + (size_t)win * 64 + lg * 8;
  for (int nt = 0; nt < 32; ++nt) {
    const unsigned short* vp = vbase + (size_t)nt * (16 * 131072);
    const bf16x8 v0 = *(const bf16x8*)vp;         // tokens lg*8..+7
    const bf16x8 v1 = *(const bf16x8*)(vp + 32);  // tokens 32+lg*8..+7
    f32x4 o = f32x4{0.f, 0.f, 0.f, 0.f};
    o = MFMA16(pa0, v0, o);
    o = MFMA16(pa1, v1, o);
#pragma unroll
    for (int r = 0; r < 4; ++r) {
      const int qq = qs + lg * 4 + r;
      const size_t p = p_base + (size_t)(qq >> 3) * 128 + (qq & 7);
      Y[p * 512 + nt * 16 + lr] = f2b(o[r]);
    }
  }
}

// ---------------- launch ----------------
extern "C" void kernel_launch(void* const* d_in, const int* in_sizes, int n_in,
                              void* d_out, int out_size, void* d_ws,
                              size_t ws_size, hipStream_t stream) {
  (void)in_sizes; (void)n_in; (void)out_size;
  const float* x = (const float*)d_in[0];
  const float* wq = (const float*)d_in[1];
  const float* bq = (const float*)d_in[2];
  const float* wk = (const float*)d_in[3];
  const float* bk = (const float*)d_in[4];
  const float* wv = (const float*)d_in[5];
  const float* bv = (const float*)d_in[6];
  const float* wo = (const float*)d_in[7];
  const float* bo = (const float*)d_in[8];

  // ws layout (shorts): wb[ wq_b | wk_b | wvT | wo_b | wvo ] 5*262144,
  // bvo fp32 @1310720 (1024 shorts), xT @2097152, xV, kws (K then Y in-place)
  const size_t NEED = (size_t)(2097152 + 3 * 67108864) * 2;
  if (ws_size < NEED) return;

  unsigned short* wb = (unsigned short*)d_ws;
  unsigned short* wvT = wb + 524288;
  unsigned short* wo_b = wb + 786432;
  unsigned short* wvo = wb + 1048576;
  float* bvo = (float*)(wb + 1310720);
  unsigned short* xT = wb + 2097152;     // [pixel][c]
  unsigned short* xV = xT + 67108864;    // [c][win*64+tok]
  unsigned short* kws = xV + 67108864;   // K, then Y (in-place per window)
  unsigned short* qws = (unsigned short*)d_out;  // Q staged (bf16), fully
                                                 // overwritten by MODE 2 fp32

  k_wconv<<<dim3(256, 3), 256, 0, stream>>>(wq, wk, wo, wb);
  k_wtrans<<<dim3(8, 8), 256, 0, stream>>>(wv, wvT);
  k_gemm<3><<<16, 256, 0, stream>>>(wo_b, wvT, nullptr, wvo);  // Wvo = Wo*Wv
  k_bvo<<<2, 256, 0, stream>>>(wo, bv, bo, bvo);
  k_transpose<<<dim3(256, 8, 8), 256, 0, stream>>>(x, xT, xV);
  k_gemm_qk<<<8192, 256, 0, stream>>>(xT, wb, bq, bk, qws, kws);
  k_attn<<<2048, 256, 0, stream>>>(qws, kws, xV, kws);
  k_gemm<2><<<4096, 256, 0, stream>>>(wvo, kws, bvo, d_out);
}

// Round 7
// 810.547 us; speedup vs baseline: 1.1418x; 1.0960x over previous
//
#include <hip/hip_runtime.h>

typedef __attribute__((ext_vector_type(8))) short bf16x8;
typedef __attribute__((ext_vector_type(4))) float f32x4;

#define MFMA16(a, b, c) __builtin_amdgcn_mfma_f32_16x16x32_bf16((a), (b), (c), 0, 0, 0)

__device__ __forceinline__ float b2f(unsigned short u) {
  unsigned int v = ((unsigned int)u) << 16;
  return __builtin_bit_cast(float, v);
}
__device__ __forceinline__ unsigned short f2b(float f) {
  unsigned int u = __builtin_bit_cast(unsigned int, f);
  u += 0x7fffu + ((u >> 16) & 1u);
  return (unsigned short)(u >> 16);
}
__device__ __forceinline__ void gload16(const void* g, void* l) {
  __builtin_amdgcn_global_load_lds(
      (const __attribute__((address_space(1))) unsigned int*)g,
      (__attribute__((address_space(3))) unsigned int*)l, 16, 0, 0);
}

// ---------------- weights fp32 -> bf16, layout preserved [o][c] ----------------
// blockIdx.y: 0 -> wq @0, 1 -> wk @262144, 2 -> wo @786432
__global__ __launch_bounds__(256) void k_wconv(
    const float* __restrict__ w0, const float* __restrict__ w1,
    const float* __restrict__ w2, unsigned short* __restrict__ out) {
  const float* src = (blockIdx.y == 0) ? w0 : (blockIdx.y == 1) ? w1 : w2;
  unsigned short* dst =
      out + (size_t)((blockIdx.y == 0) ? 0 : (blockIdx.y == 1) ? 262144 : 786432);
  const int i = (blockIdx.x * 256 + threadIdx.x) * 4;
  const float4 v = *(const float4*)(src + i);
  uint2 p;
  p.x = (unsigned int)f2b(v.x) | ((unsigned int)f2b(v.y) << 16);
  p.y = (unsigned int)f2b(v.z) | ((unsigned int)f2b(v.w) << 16);
  *(uint2*)(dst + i) = p;
}

// ---------------- wv fp32 [cv][j] -> wvT bf16 [j][cv] ----------------
__global__ __launch_bounds__(256) void k_wtrans(
    const float* __restrict__ in, unsigned short* __restrict__ out) {
  __shared__ unsigned short tile[64][72];
  const int r0 = blockIdx.x << 6, s0 = blockIdx.y << 6;  // r=j, s=cv
  const int t = threadIdx.x;
  {
    const int sl = t >> 3, rl = (t & 7) << 3;
#pragma unroll
    for (int pass = 0; pass < 2; ++pass) {
      const int s = sl + pass * 32;
      const float* src = in + (size_t)(s0 + s) * 512 + r0 + rl;
      const float4 f0 = ((const float4*)src)[0];
      const float4 f1 = ((const float4*)src)[1];
      tile[rl + 0][s] = f2b(f0.x);
      tile[rl + 1][s] = f2b(f0.y);
      tile[rl + 2][s] = f2b(f0.z);
      tile[rl + 3][s] = f2b(f0.w);
      tile[rl + 4][s] = f2b(f1.x);
      tile[rl + 5][s] = f2b(f1.y);
      tile[rl + 6][s] = f2b(f1.z);
      tile[rl + 7][s] = f2b(f1.w);
    }
  }
  __syncthreads();
  {
    const int rl = t >> 3, sl = (t & 7) << 3;
#pragma unroll
    for (int pass = 0; pass < 2; ++pass) {
      const int r = rl + pass * 32;
      uint4 v = *(const uint4*)&tile[r][sl];
      *(uint4*)(out + (size_t)(r0 + r) * 512 + s0 + sl) = v;
    }
  }
}

// ---------------- bvo[o] = bo[o] + sum_j wo[o][j]*bv[j]  (fp32) ----------------
__global__ __launch_bounds__(256) void k_bvo(
    const float* __restrict__ wo, const float* __restrict__ bv,
    const float* __restrict__ bo, float* __restrict__ bvo) {
  const int o = blockIdx.x * 256 + threadIdx.x;
  float acc = bo[o];
  const float* row = wo + (size_t)o * 512;
  for (int j = 0; j < 512; ++j) acc += row[j] * bv[j];
  bvo[o] = acc;
}

// ---------- K0: x fp32 [b][c][p] -> xT bf16 [pixel][c]  AND  xV bf16 [c][win*64+tok] ----------
__global__ __launch_bounds__(256) void k_transpose(
    const float* __restrict__ X, unsigned short* __restrict__ XT,
    unsigned short* __restrict__ XV) {
  __shared__ unsigned short tile[64][72];
  const int p0 = blockIdx.x << 6, c0 = blockIdx.y << 6, b = blockIdx.z;
  const float* xb = X + (size_t)b * 8388608u;
  unsigned short* xtb = XT + (size_t)b * 8388608u;
  const int t = threadIdx.x;
  const int h = p0 >> 7, th2 = h >> 3, hrow = h & 7;
  const int widb = b * 256 + th2 * 16 + ((p0 & 127) >> 3);
  {
    const int cl = t >> 3, pl = (t & 7) << 3;
    const int widx = t & 7;
#pragma unroll
    for (int pass = 0; pass < 2; ++pass) {
      const int c = cl + pass * 32;
      const float* src = xb + (size_t)(c0 + c) * 16384 + p0 + pl;
      const float4 f0 = ((const float4*)src)[0];
      const float4 f1 = ((const float4*)src)[1];
      unsigned short r8[8];
      r8[0] = f2b(f0.x); r8[1] = f2b(f0.y); r8[2] = f2b(f0.z); r8[3] = f2b(f0.w);
      r8[4] = f2b(f1.x); r8[5] = f2b(f1.y); r8[6] = f2b(f1.z); r8[7] = f2b(f1.w);
#pragma unroll
      for (int i = 0; i < 8; ++i) tile[pl + i][c] = r8[i];
      *(uint4*)(XV + (size_t)(c0 + c) * 131072 +
                (size_t)(widb + widx) * 64 + hrow * 8) = *(const uint4*)r8;
    }
  }
  __syncthreads();
  {
    const int pl = t >> 3, cl = (t & 7) << 3;
#pragma unroll
    for (int pass = 0; pass < 2; ++pass) {
      const int p = pl + pass * 32;
      uint4 v = *(const uint4*)&tile[p][cl];
      *(uint4*)(xtb + (size_t)(p0 + p) * 512 + c0 + cl) = v;
    }
  }
}

// ================= 256x256-tile GEMM, BK=64, 8 waves, T3-minimum pipeline ==============
// C[m][n] = sum_k A[m][k]*B[n][k] (+bias), K=512. Double-buffered LDS (128 KiB),
// one barrier per K-step: STAGE(next)->compute(cur)->sync.
// MODE 0: fused Q+K proj. A=xT; B=W+mat*262144; bf16 C[mat][m=pixel][n], +bias[n].
// MODE 2: final.        A=wvo; B=Y;  fp32 C->(B,C,H,W) from [m=chan][n=pixel], +bias[m].
// MODE 3: wvo precompute. A=wo_b; B=wvT; bf16 C[m][n] ldc=512, no bias.
template <int MODE>
__global__ __launch_bounds__(512, 2) void k_gemm256(
    const unsigned short* __restrict__ A, const unsigned short* __restrict__ W,
    const float* __restrict__ bias0, const float* __restrict__ bias1,
    void* __restrict__ C0v, void* __restrict__ C1v) {
  __shared__ unsigned short lsA[2][256 * 64];
  __shared__ unsigned short lsB[2][256 * 64];
  const int bid = blockIdx.x;
  int mt, nt, mat = 0;
  if (MODE == 0) {
    const int work = ((bid & 7) << 8) + (bid >> 3);  // XCD-chunked, grid 2048
    mt = work >> 2;
    const int ny = work & 3;
    mat = ny >> 1; nt = ny & 1;
  } else if (MODE == 2) {
    const int work = ((bid & 7) << 7) + (bid >> 3);  // XCD-chunked, grid 1024
    nt = work >> 1; mt = work & 1;
  } else {
    mt = bid & 1; nt = bid >> 1;                     // grid 4
  }
  const unsigned short* B = (MODE == 0) ? (W + mat * 262144) : W;
  const int m0 = mt << 8, n0 = nt << 8;

  const int t = threadIdx.x;
  const int w = t >> 6, l = t & 63;
  const int lr = l & 15, lg = l >> 4;
  const int wr = w >> 2, wc = w & 3;
  const int srow = t >> 3;        // 0..63 (+64*i per stage instr)
  const int scol = (t & 7) << 3;  // shorts
  const int ra = wr << 7;         // wave rows: 0 / 128
  const int rb = wc << 6;         // wave cols: 0/64/128/192

  f32x4 acc[8][4];
#pragma unroll
  for (int i = 0; i < 8; ++i)
#pragma unroll
    for (int j = 0; j < 4; ++j) acc[i][j] = f32x4{0.f, 0.f, 0.f, 0.f};

  // stage K-tile kt into buffer buf (LDS dest = wave-uniform base + lane*16)
  auto stage = [&](int kt, int buf) {
    const int k0 = kt << 6;
#pragma unroll
    for (int i = 0; i < 4; ++i) {
      gload16(A + (size_t)(m0 + srow + (i << 6)) * 512 + k0 + scol,
              &lsA[buf][(srow + (i << 6)) * 64 + scol]);
      gload16(B + (size_t)(n0 + srow + (i << 6)) * 512 + k0 + scol,
              &lsB[buf][(srow + (i << 6)) * 64 + scol]);
    }
  };
  auto compute = [&](int buf) {
#pragma unroll
    for (int kk = 0; kk < 2; ++kk) {
      bf16x8 af[8], bfv[4];
#pragma unroll
      for (int i = 0; i < 8; ++i)
        af[i] =
            *(const bf16x8*)&lsA[buf][(ra + i * 16 + lr) * 64 + kk * 32 + lg * 8];
#pragma unroll
      for (int j = 0; j < 4; ++j)
        bfv[j] =
            *(const bf16x8*)&lsB[buf][(rb + j * 16 + lr) * 64 + kk * 32 + lg * 8];
#pragma unroll
      for (int i = 0; i < 8; ++i)
#pragma unroll
        for (int j = 0; j < 4; ++j)
          acc[i][j] = MFMA16(af[i], bfv[j], acc[i][j]);
    }
  };

  stage(0, 0);
  __syncthreads();
  int cur = 0;
  for (int kt = 0; kt < 7; ++kt) {
    stage(kt + 1, cur ^ 1);  // prefetch overlaps the MFMA phase below
    compute(cur);
    __syncthreads();         // drains prefetch vmcnt; buf swap safe
    cur ^= 1;
  }
  compute(cur);

  // ---------------- epilogue ----------------
#pragma unroll
  for (int i = 0; i < 8; ++i) {
    const int cmb = m0 + ra + i * 16 + lg * 4;
#pragma unroll
    for (int j = 0; j < 4; ++j) {
      const int cn = n0 + rb + j * 16 + lr;
#pragma unroll
      for (int r = 0; r < 4; ++r) {
        const int cm = cmb + r;
        if (MODE == 0) {
          unsigned short* C = mat ? (unsigned short*)C1v : (unsigned short*)C0v;
          const float bn = (mat ? bias1 : bias0)[cn];
          C[(size_t)cm * 512 + cn] = f2b(acc[i][j][r] + bn);
        } else if (MODE == 2) {
          const float val = acc[i][j][r] + bias0[cm];
          const int bb = cn >> 14, p = cn & 16383;
          ((float*)C0v)[(size_t)bb * 8388608 + (size_t)cm * 16384 + p] = val;
        } else {
          ((unsigned short*)C0v)[(size_t)cm * 512 + cn] = f2b(acc[i][j][r]);
        }
      }
    }
  }
}

// ---------------- K2: window attention + PV against raw x ----------------
// Q,K: [pixel][c] bf16.  XV: [c][win*64+tok] bf16.  Y out -> K buffer (in-place,
// window-private rows), layout [pixel][c] bf16.
__global__ __launch_bounds__(256) void k_attn(
    const unsigned short* __restrict__ Q, const unsigned short* __restrict__ K,
    const unsigned short* __restrict__ XV, unsigned short* __restrict__ Y) {
  __shared__ unsigned short P_lds[64][72];
  const int win = ((blockIdx.x & 7) << 8) + (blockIdx.x >> 3);
  const int b = win >> 8, th = (win >> 4) & 15, tw = win & 15;
  const size_t p_base = (size_t)b * 16384 + (size_t)th * 1024 + (size_t)tw * 8;
  const int t = threadIdx.x, w = t >> 6, l = t & 63;
  const int lr = l & 15, lg = l >> 4;
  const int qs = w << 4;
  const int qtok = qs + lr;
  const unsigned short* qrow =
      Q + (p_base + (size_t)(qtok >> 3) * 128 + (qtok & 7)) * 512;
  const unsigned short* krow =
      K + (p_base + (size_t)(lr >> 3) * 128 + (lr & 7)) * 512;

  // S'[k_tok][q] = mfma(A=K, B=Q): lane holds q=lr, k = mt*16 + lg*4 + j
  f32x4 acc[4];
#pragma unroll
  for (int i = 0; i < 4; ++i) acc[i] = f32x4{0.f, 0.f, 0.f, 0.f};

  for (int cs = 0; cs < 16; ++cs) {
    const int co = cs * 32 + lg * 8;
    const bf16x8 bq = *(const bf16x8*)(qrow + co);
#pragma unroll
    for (int mt = 0; mt < 4; ++mt) {
      const bf16x8 ak = *(const bf16x8*)(krow + (size_t)mt * 131072 + co);
      acc[mt] = MFMA16(ak, bq, acc[mt]);
    }
  }

  const float scale = 0.044194173824159216f;  // 1/sqrt(512)
  float pv[4][4];
  float mx = -3.0e38f;
#pragma unroll
  for (int mt = 0; mt < 4; ++mt)
#pragma unroll
    for (int j = 0; j < 4; ++j) {
      const float s = acc[mt][j] * scale;
      pv[mt][j] = s;
      mx = fmaxf(mx, s);
    }
  mx = fmaxf(mx, __shfl_xor(mx, 16));
  mx = fmaxf(mx, __shfl_xor(mx, 32));
  float sum = 0.f;
#pragma unroll
  for (int mt = 0; mt < 4; ++mt)
#pragma unroll
    for (int j = 0; j < 4; ++j) {
      const float e = __expf(pv[mt][j] - mx);
      pv[mt][j] = e;
      sum += e;
    }
  sum += __shfl_xor(sum, 16);
  sum += __shfl_xor(sum, 32);
  const float inv = 1.f / sum;

  // P[q][k] -> LDS (bf16, padded pitch 72)
#pragma unroll
  for (int mt = 0; mt < 4; ++mt)
#pragma unroll
    for (int j = 0; j < 4; j += 2) {
      const unsigned int pk =
          (unsigned int)f2b(pv[mt][j] * inv) |
          ((unsigned int)f2b(pv[mt][j + 1] * inv) << 16);
      *(unsigned int*)&P_lds[qtok][mt * 16 + lg * 4 + j] = pk;
    }
  __syncthreads();

  // PV: Y[q][c] = mfma(A=P[q][tok], B=X[tok][c]) from window-contiguous XV
  const bf16x8 pa0 = *(const bf16x8*)&P_lds[qtok][lg * 8];
  const bf16x8 pa1 = *(const bf16x8*)&P_lds[qtok][32 + lg * 8];
  const unsigned short* vbase =
      XV + (size_t)lr * 131072 + (size_t)win * 64 + lg * 8;
  for (int nt = 0; nt < 32; ++nt) {
    const unsigned short* vp = vbase + (size_t)nt * (16 * 131072);
    const bf16x8 v0 = *(const bf16x8*)vp;         // tokens lg*8..+7
    const bf16x8 v1 = *(const bf16x8*)(vp + 32);  // tokens 32+lg*8..+7
    f32x4 o = f32x4{0.f, 0.f, 0.f, 0.f};
    o = MFMA16(pa0, v0, o);
    o = MFMA16(pa1, v1, o);
#pragma unroll
    for (int r = 0; r < 4; ++r) {
      const int qq = qs + lg * 4 + r;
      const size_t p = p_base + (size_t)(qq >> 3) * 128 + (qq & 7);
      Y[p * 512 + nt * 16 + lr] = f2b(o[r]);
    }
  }
}

// ---------------- launch ----------------
extern "C" void kernel_launch(void* const* d_in, const int* in_sizes, int n_in,
                              void* d_out, int out_size, void* d_ws,
                              size_t ws_size, hipStream_t stream) {
  (void)in_sizes; (void)n_in; (void)out_size;
  const float* x = (const float*)d_in[0];
  const float* wq = (const float*)d_in[1];
  const float* bq = (const float*)d_in[2];
  const float* wk = (const float*)d_in[3];
  const float* bk = (const float*)d_in[4];
  const float* wv = (const float*)d_in[5];
  const float* bv = (const float*)d_in[6];
  const float* wo = (const float*)d_in[7];
  const float* bo = (const float*)d_in[8];

  // ws layout (shorts): wb[ wq_b | wk_b | wvT | wo_b | wvo ] 5*262144,
  // bvo fp32 @1310720 (1024 shorts), xT @2097152, xV, kws (K then Y in-place)
  const size_t NEED = (size_t)(2097152 + 3 * 67108864) * 2;
  if (ws_size < NEED) return;

  unsigned short* wb = (unsigned short*)d_ws;
  unsigned short* wvT = wb + 524288;
  unsigned short* wo_b = wb + 786432;
  unsigned short* wvo = wb + 1048576;
  float* bvo = (float*)(wb + 1310720);
  unsigned short* xT = wb + 2097152;     // [pixel][c]
  unsigned short* xV = xT + 67108864;    // [c][win*64+tok]
  unsigned short* kws = xV + 67108864;   // K, then Y (in-place per window)
  unsigned short* qws = (unsigned short*)d_out;  // Q staged (bf16), fully
                                                 // overwritten by MODE 2 fp32

  k_wconv<<<dim3(256, 3), 256, 0, stream>>>(wq, wk, wo, wb);
  k_wtrans<<<dim3(8, 8), 256, 0, stream>>>(wv, wvT);
  k_gemm256<3><<<4, 512, 0, stream>>>(wo_b, wvT, nullptr, nullptr, wvo, nullptr);
  k_bvo<<<2, 256, 0, stream>>>(wo, bv, bo, bvo);
  k_transpose<<<dim3(256, 8, 8), 256, 0, stream>>>(x, xT, xV);
  k_gemm256<0><<<2048, 512, 0, stream>>>(xT, wb, bq, bk, qws, kws);
  k_attn<<<2048, 256, 0, stream>>>(qws, kws, xV, kws);
  k_gemm256<2><<<1024, 512, 0, stream>>>(wvo, kws, bvo, nullptr, d_out, nullptr);
}

// Round 8
// 781.406 us; speedup vs baseline: 1.1844x; 1.0373x over previous
//
#include <hip/hip_runtime.h>

typedef __attribute__((ext_vector_type(8))) short bf16x8;
typedef __attribute__((ext_vector_type(4))) float f32x4;

#define MFMA16(a, b, c) __builtin_amdgcn_mfma_f32_16x16x32_bf16((a), (b), (c), 0, 0, 0)

__device__ __forceinline__ float b2f(unsigned short u) {
  unsigned int v = ((unsigned int)u) << 16;
  return __builtin_bit_cast(float, v);
}
__device__ __forceinline__ unsigned short f2b(float f) {
  unsigned int u = __builtin_bit_cast(unsigned int, f);
  u += 0x7fffu + ((u >> 16) & 1u);
  return (unsigned short)(u >> 16);
}
__device__ __forceinline__ void gload16(const void* g, void* l) {
  __builtin_amdgcn_global_load_lds(
      (const __attribute__((address_space(1))) unsigned int*)g,
      (__attribute__((address_space(3))) unsigned int*)l, 16, 0, 0);
}

// ---------------- weights fp32 -> bf16, layout preserved [o][c] ----------------
__global__ __launch_bounds__(256) void k_wconv(
    const float* __restrict__ w0, const float* __restrict__ w1,
    const float* __restrict__ w2, unsigned short* __restrict__ out) {
  const float* src = (blockIdx.y == 0) ? w0 : (blockIdx.y == 1) ? w1 : w2;
  unsigned short* dst =
      out + (size_t)((blockIdx.y == 0) ? 0 : (blockIdx.y == 1) ? 262144 : 786432);
  const int i = (blockIdx.x * 256 + threadIdx.x) * 4;
  const float4 v = *(const float4*)(src + i);
  uint2 p;
  p.x = (unsigned int)f2b(v.x) | ((unsigned int)f2b(v.y) << 16);
  p.y = (unsigned int)f2b(v.z) | ((unsigned int)f2b(v.w) << 16);
  *(uint2*)(dst + i) = p;
}

// ---------------- wv fp32 [cv][j] -> wvT bf16 [j][cv] ----------------
__global__ __launch_bounds__(256) void k_wtrans(
    const float* __restrict__ in, unsigned short* __restrict__ out) {
  __shared__ unsigned short tile[64][72];
  const int r0 = blockIdx.x << 6, s0 = blockIdx.y << 6;
  const int t = threadIdx.x;
  {
    const int sl = t >> 3, rl = (t & 7) << 3;
#pragma unroll
    for (int pass = 0; pass < 2; ++pass) {
      const int s = sl + pass * 32;
      const float* src = in + (size_t)(s0 + s) * 512 + r0 + rl;
      const float4 f0 = ((const float4*)src)[0];
      const float4 f1 = ((const float4*)src)[1];
      tile[rl + 0][s] = f2b(f0.x);
      tile[rl + 1][s] = f2b(f0.y);
      tile[rl + 2][s] = f2b(f0.z);
      tile[rl + 3][s] = f2b(f0.w);
      tile[rl + 4][s] = f2b(f1.x);
      tile[rl + 5][s] = f2b(f1.y);
      tile[rl + 6][s] = f2b(f1.z);
      tile[rl + 7][s] = f2b(f1.w);
    }
  }
  __syncthreads();
  {
    const int rl = t >> 3, sl = (t & 7) << 3;
#pragma unroll
    for (int pass = 0; pass < 2; ++pass) {
      const int r = rl + pass * 32;
      uint4 v = *(const uint4*)&tile[r][sl];
      *(uint4*)(out + (size_t)(r0 + r) * 512 + s0 + sl) = v;
    }
  }
}

// ---------------- bvo[o] = bo[o] + sum_j wo[o][j]*bv[j]  (fp32) ----------------
__global__ __launch_bounds__(256) void k_bvo(
    const float* __restrict__ wo, const float* __restrict__ bv,
    const float* __restrict__ bo, float* __restrict__ bvo) {
  const int o = blockIdx.x * 256 + threadIdx.x;
  float acc = bo[o];
  const float* row = wo + (size_t)o * 512;
  for (int j = 0; j < 512; ++j) acc += row[j] * bv[j];
  bvo[o] = acc;
}

// ---------- K0: x fp32 [b][c][p] -> xT bf16 [pixel][c]  AND  xV bf16 [c][win*64+tok] ----------
__global__ __launch_bounds__(256) void k_transpose(
    const float* __restrict__ X, unsigned short* __restrict__ XT,
    unsigned short* __restrict__ XV) {
  __shared__ unsigned short tile[64][72];
  const int p0 = blockIdx.x << 6, c0 = blockIdx.y << 6, b = blockIdx.z;
  const float* xb = X + (size_t)b * 8388608u;
  unsigned short* xtb = XT + (size_t)b * 8388608u;
  const int t = threadIdx.x;
  const int h = p0 >> 7, th2 = h >> 3, hrow = h & 7;
  const int widb = b * 256 + th2 * 16 + ((p0 & 127) >> 3);
  {
    const int cl = t >> 3, pl = (t & 7) << 3;
    const int widx = t & 7;
#pragma unroll
    for (int pass = 0; pass < 2; ++pass) {
      const int c = cl + pass * 32;
      const float* src = xb + (size_t)(c0 + c) * 16384 + p0 + pl;
      const float4 f0 = ((const float4*)src)[0];
      const float4 f1 = ((const float4*)src)[1];
      unsigned short r8[8];
      r8[0] = f2b(f0.x); r8[1] = f2b(f0.y); r8[2] = f2b(f0.z); r8[3] = f2b(f0.w);
      r8[4] = f2b(f1.x); r8[5] = f2b(f1.y); r8[6] = f2b(f1.z); r8[7] = f2b(f1.w);
#pragma unroll
      for (int i = 0; i < 8; ++i) tile[pl + i][c] = r8[i];
      *(uint4*)(XV + (size_t)(c0 + c) * 131072 +
                (size_t)(widb + widx) * 64 + hrow * 8) = *(const uint4*)r8;
    }
  }
  __syncthreads();
  {
    const int pl = t >> 3, cl = (t & 7) << 3;
#pragma unroll
    for (int pass = 0; pass < 2; ++pass) {
      const int p = pl + pass * 32;
      uint4 v = *(const uint4*)&tile[p][cl];
      *(uint4*)(xtb + (size_t)(p0 + p) * 512 + c0 + cl) = v;
    }
  }
}

// ========== 256x256 GEMM, K=512 as 16 K-subtiles of 32, depth-3 counted pipeline ==========
// LDS: 4 buffers x ([256][32] A + [256][32] B) shorts = 128 KiB. Row stride 64 B
// -> fragment reads bank-uniform (no swizzle needed). Raw s_barrier + counted
// vmcnt (never 0 in steady state). 8 waves (2Mx4N), per-wave 128x64 output.
// MODE 0: fused Q+K proj. A=xT; B=W+mat*262144; bf16 C[mat][m=pixel][n], +bias[n].
// MODE 2: final. A=wvo; B=Y; fp32 C->(B,C,H,W) from [m=chan][n=pixel], +bias[m].
// MODE 3: wvo precompute. A=wo_b; B=wvT; bf16 C[m][n] ldc=512, no bias.
template <int MODE>
__global__ __launch_bounds__(512, 2) void k_gemm256(
    const unsigned short* __restrict__ A, const unsigned short* __restrict__ W,
    const float* __restrict__ bias0, const float* __restrict__ bias1,
    void* __restrict__ C0v, void* __restrict__ C1v) {
  __shared__ unsigned short lsA[4][256 * 32];
  __shared__ unsigned short lsB[4][256 * 32];
  const int bid = blockIdx.x;
  int mt, nt, mat = 0;
  if (MODE == 0) {
    const int work = ((bid & 7) << 8) + (bid >> 3);  // XCD-chunked, grid 2048
    mt = work >> 2;
    const int ny = work & 3;
    mat = ny >> 1; nt = ny & 1;
  } else if (MODE == 2) {
    const int work = ((bid & 7) << 7) + (bid >> 3);  // XCD-chunked, grid 1024
    nt = work >> 1; mt = work & 1;
  } else {
    mt = bid & 1; nt = bid >> 1;                     // grid 4
  }
  const unsigned short* B = (MODE == 0) ? (W + mat * 262144) : W;
  const int m0 = mt << 8, n0 = nt << 8;

  const int t = threadIdx.x;
  const int l = t & 63;
  const int lr = l & 15, lg = l >> 4;
  const int w = t >> 6;
  const int wr = w >> 2, wc = w & 3;
  const int ra = wr << 7, rb = wc << 6;
  const int srowS = t >> 2;        // 0..127 (+128 for 2nd gload)
  const int scolS = (t & 3) << 3;  // shorts

  f32x4 acc[8][4];
#pragma unroll
  for (int i = 0; i < 8; ++i)
#pragma unroll
    for (int j = 0; j < 4; ++j) acc[i][j] = f32x4{0.f, 0.f, 0.f, 0.f};

  // stage K-subtile kt (A+B, 4 gload_lds; LDS dest linear in lane)
  auto stage = [&](int kt) {
    const int buf = kt & 3, k0 = kt << 5;
#pragma unroll
    for (int hh = 0; hh < 2; ++hh) {
      gload16(A + (size_t)(m0 + srowS + hh * 128) * 512 + k0 + scolS,
              &lsA[buf][(srowS + hh * 128) * 32 + scolS]);
      gload16(B + (size_t)(n0 + srowS + hh * 128) * 512 + k0 + scolS,
              &lsB[buf][(srowS + hh * 128) * 32 + scolS]);
    }
  };
  // compute K-subtile kt: 12 ds_read_b128 + 32 MFMA
  auto compute = [&](int kt) {
    const int buf = kt & 3;
    bf16x8 af[8], bfv[4];
#pragma unroll
    for (int i = 0; i < 8; ++i)
      af[i] = *(const bf16x8*)&lsA[buf][(ra + i * 16 + lr) * 32 + lg * 8];
#pragma unroll
    for (int j = 0; j < 4; ++j)
      bfv[j] = *(const bf16x8*)&lsB[buf][(rb + j * 16 + lr) * 32 + lg * 8];
    __builtin_amdgcn_s_setprio(1);
#pragma unroll
    for (int i = 0; i < 8; ++i)
#pragma unroll
      for (int j = 0; j < 4; ++j)
        acc[i][j] = MFMA16(af[i], bfv[j], acc[i][j]);
    __builtin_amdgcn_s_setprio(0);
  };

  stage(0); stage(1); stage(2);  // depth-3 prologue (12 loads in flight)

#define GITER(kt, vm)                                        \
  asm volatile("s_waitcnt vmcnt(" #vm ")" ::: "memory");     \
  __builtin_amdgcn_s_barrier();                              \
  __builtin_amdgcn_sched_barrier(0);                         \
  if ((kt) + 3 < 16) stage((kt) + 3);                        \
  compute(kt);                                               \
  __builtin_amdgcn_sched_barrier(0);                         \
  __builtin_amdgcn_s_barrier();

  GITER(0, 8)  GITER(1, 8)  GITER(2, 8)  GITER(3, 8)
  GITER(4, 8)  GITER(5, 8)  GITER(6, 8)  GITER(7, 8)
  GITER(8, 8)  GITER(9, 8)  GITER(10, 8) GITER(11, 8)
  GITER(12, 8) GITER(13, 8) GITER(14, 4) GITER(15, 0)
#undef GITER

  // ---------------- epilogue ----------------
#pragma unroll
  for (int i = 0; i < 8; ++i) {
    const int cmb = m0 + ra + i * 16 + lg * 4;
#pragma unroll
    for (int j = 0; j < 4; ++j) {
      const int cn = n0 + rb + j * 16 + lr;
#pragma unroll
      for (int r = 0; r < 4; ++r) {
        const int cm = cmb + r;
        if (MODE == 0) {
          unsigned short* C = mat ? (unsigned short*)C1v : (unsigned short*)C0v;
          const float bn = (mat ? bias1 : bias0)[cn];
          C[(size_t)cm * 512 + cn] = f2b(acc[i][j][r] + bn);
        } else if (MODE == 2) {
          const float val = acc[i][j][r] + bias0[cm];
          const int bb = cn >> 14, p = cn & 16383;
          ((float*)C0v)[(size_t)bb * 8388608 + (size_t)cm * 16384 + p] = val;
        } else {
          ((unsigned short*)C0v)[(size_t)cm * 512 + cn] = f2b(acc[i][j][r]);
        }
      }
    }
  }
}

// ---------------- K2: window attention + PV against raw x ----------------
__global__ __launch_bounds__(256) void k_attn(
    const unsigned short* __restrict__ Q, const unsigned short* __restrict__ K,
    const unsigned short* __restrict__ XV, unsigned short* __restrict__ Y) {
  __shared__ unsigned short P_lds[64][72];
  const int win = ((blockIdx.x & 7) << 8) + (blockIdx.x >> 3);
  const int b = win >> 8, th = (win >> 4) & 15, tw = win & 15;
  const size_t p_base = (size_t)b * 16384 + (size_t)th * 1024 + (size_t)tw * 8;
  const int t = threadIdx.x, w = t >> 6, l = t & 63;
  const int lr = l & 15, lg = l >> 4;
  const int qs = w << 4;
  const int qtok = qs + lr;
  const unsigned short* qrow =
      Q + (p_base + (size_t)(qtok >> 3) * 128 + (qtok & 7)) * 512;
  const unsigned short* krow =
      K + (p_base + (size_t)(lr >> 3) * 128 + (lr & 7)) * 512;

  f32x4 acc[4];
#pragma unroll
  for (int i = 0; i < 4; ++i) acc[i] = f32x4{0.f, 0.f, 0.f, 0.f};

  for (int cs = 0; cs < 16; ++cs) {
    const int co = cs * 32 + lg * 8;
    const bf16x8 bq = *(const bf16x8*)(qrow + co);
#pragma unroll
    for (int mt = 0; mt < 4; ++mt) {
      const bf16x8 ak = *(const bf16x8*)(krow + (size_t)mt * 131072 + co);
      acc[mt] = MFMA16(ak, bq, acc[mt]);
    }
  }

  const float scale = 0.044194173824159216f;  // 1/sqrt(512)
  float pv[4][4];
  float mx = -3.0e38f;
#pragma unroll
  for (int mt = 0; mt < 4; ++mt)
#pragma unroll
    for (int j = 0; j < 4; ++j) {
      const float s = acc[mt][j] * scale;
      pv[mt][j] = s;
      mx = fmaxf(mx, s);
    }
  mx = fmaxf(mx, __shfl_xor(mx, 16));
  mx = fmaxf(mx, __shfl_xor(mx, 32));
  float sum = 0.f;
#pragma unroll
  for (int mt = 0; mt < 4; ++mt)
#pragma unroll
    for (int j = 0; j < 4; ++j) {
      const float e = __expf(pv[mt][j] - mx);
      pv[mt][j] = e;
      sum += e;
    }
  sum += __shfl_xor(sum, 16);
  sum += __shfl_xor(sum, 32);
  const float inv = 1.f / sum;

#pragma unroll
  for (int mt = 0; mt < 4; ++mt)
#pragma unroll
    for (int j = 0; j < 4; j += 2) {
      const unsigned int pk =
          (unsigned int)f2b(pv[mt][j] * inv) |
          ((unsigned int)f2b(pv[mt][j + 1] * inv) << 16);
      *(unsigned int*)&P_lds[qtok][mt * 16 + lg * 4 + j] = pk;
    }
  __syncthreads();

  const bf16x8 pa0 = *(const bf16x8*)&P_lds[qtok][lg * 8];
  const bf16x8 pa1 = *(const bf16x8*)&P_lds[qtok][32 + lg * 8];
  const unsigned short* vbase =
      XV + (size_t)lr * 131072 + (size_t)win * 64 + lg * 8;
  for (int nt = 0; nt < 32; ++nt) {
    const unsigned short* vp = vbase + (size_t)nt * (16 * 131072);
    const bf16x8 v0 = *(const bf16x8*)vp;
    const bf16x8 v1 = *(const bf16x8*)(vp + 32);
    f32x4 o = f32x4{0.f, 0.f, 0.f, 0.f};
    o = MFMA16(pa0, v0, o);
    o = MFMA16(pa1, v1, o);
#pragma unroll
    for (int r = 0; r < 4; ++r) {
      const int qq = qs + lg * 4 + r;
      const size_t p = p_base + (size_t)(qq >> 3) * 128 + (qq & 7);
      Y[p * 512 + nt * 16 + lr] = f2b(o[r]);
    }
  }
}

// ---------------- launch ----------------
extern "C" void kernel_launch(void* const* d_in, const int* in_sizes, int n_in,
                              void* d_out, int out_size, void* d_ws,
                              size_t ws_size, hipStream_t stream) {
  (void)in_sizes; (void)n_in; (void)out_size;
  const float* x = (const float*)d_in[0];
  const float* wq = (const float*)d_in[1];
  const float* bq = (const float*)d_in[2];
  const float* wk = (const float*)d_in[3];
  const float* bk = (const float*)d_in[4];
  const float* wv = (const float*)d_in[5];
  const float* bv = (const float*)d_in[6];
  const float* wo = (const float*)d_in[7];
  const float* bo = (const float*)d_in[8];

  const size_t NEED = (size_t)(2097152 + 3 * 67108864) * 2;
  if (ws_size < NEED) return;

  unsigned short* wb = (unsigned short*)d_ws;
  unsigned short* wvT = wb + 524288;
  unsigned short* wo_b = wb + 786432;
  unsigned short* wvo = wb + 1048576;
  float* bvo = (float*)(wb + 1310720);
  unsigned short* xT = wb + 2097152;     // [pixel][c]
  unsigned short* xV = xT + 67108864;    // [c][win*64+tok]
  unsigned short* kws = xV + 67108864;   // K, then Y (in-place per window)
  unsigned short* qws = (unsigned short*)d_out;  // Q staged (bf16), fully
                                                 // overwritten by MODE 2 fp32

  k_wconv<<<dim3(256, 3), 256, 0, stream>>>(wq, wk, wo, wb);
  k_wtrans<<<dim3(8, 8), 256, 0, stream>>>(wv, wvT);
  k_gemm256<3><<<4, 512, 0, stream>>>(wo_b, wvT, nullptr, nullptr, wvo, nullptr);
  k_bvo<<<2, 256, 0, stream>>>(wo, bv, bo, bvo);
  k_transpose<<<dim3(256, 8, 8), 256, 0, stream>>>(x, xT, xV);
  k_gemm256<0><<<2048, 512, 0, stream>>>(xT, wb, bq, bk, qws, kws);
  k_attn<<<2048, 256, 0, stream>>>(qws, kws, xV, kws);
  k_gemm256<2><<<1024, 512, 0, stream>>>(wvo, kws, bvo, nullptr, d_out, nullptr);
}

// Round 9
// 719.036 us; speedup vs baseline: 1.2871x; 1.0867x over previous
//
#include <hip/hip_runtime.h>

typedef __attribute__((ext_vector_type(8))) short bf16x8;
typedef __attribute__((ext_vector_type(4))) float f32x4;

#define MFMA16(a, b, c) __builtin_amdgcn_mfma_f32_16x16x32_bf16((a), (b), (c), 0, 0, 0)

__device__ __forceinline__ float b2f(unsigned short u) {
  unsigned int v = ((unsigned int)u) << 16;
  return __builtin_bit_cast(float, v);
}
__device__ __forceinline__ unsigned short f2b(float f) {
  unsigned int u = __builtin_bit_cast(unsigned int, f);
  u += 0x7fffu + ((u >> 16) & 1u);
  return (unsigned short)(u >> 16);
}
__device__ __forceinline__ void gload16(const void* g, void* l) {
  __builtin_amdgcn_global_load_lds(
      (const __attribute__((address_space(1))) unsigned int*)g,
      (__attribute__((address_space(3))) unsigned int*)l, 16, 0, 0);
}

// ---------------- wo fp32 -> bf16, layout preserved [o][c] ----------------
__global__ __launch_bounds__(256) void k_wconv(
    const float* __restrict__ src, unsigned short* __restrict__ dst) {
  const int i = (blockIdx.x * 256 + threadIdx.x) * 4;
  const float4 v = *(const float4*)(src + i);
  uint2 p;
  p.x = (unsigned int)f2b(v.x) | ((unsigned int)f2b(v.y) << 16);
  p.y = (unsigned int)f2b(v.z) | ((unsigned int)f2b(v.w) << 16);
  *(uint2*)(dst + i) = p;
}

// ---------------- w fp32 [a][b] -> bf16 [b][a] (512x512) ----------------
__global__ __launch_bounds__(256) void k_wtrans(
    const float* __restrict__ in, unsigned short* __restrict__ out) {
  __shared__ unsigned short tile[64][72];
  const int r0 = blockIdx.x << 6, s0 = blockIdx.y << 6;
  const int t = threadIdx.x;
  {
    const int sl = t >> 3, rl = (t & 7) << 3;
#pragma unroll
    for (int pass = 0; pass < 2; ++pass) {
      const int s = sl + pass * 32;
      const float* src = in + (size_t)(s0 + s) * 512 + r0 + rl;
      const float4 f0 = ((const float4*)src)[0];
      const float4 f1 = ((const float4*)src)[1];
      tile[rl + 0][s] = f2b(f0.x);
      tile[rl + 1][s] = f2b(f0.y);
      tile[rl + 2][s] = f2b(f0.z);
      tile[rl + 3][s] = f2b(f0.w);
      tile[rl + 4][s] = f2b(f1.x);
      tile[rl + 5][s] = f2b(f1.y);
      tile[rl + 6][s] = f2b(f1.z);
      tile[rl + 7][s] = f2b(f1.w);
    }
  }
  __syncthreads();
  {
    const int rl = t >> 3, sl = (t & 7) << 3;
#pragma unroll
    for (int pass = 0; pass < 2; ++pass) {
      const int r = rl + pass * 32;
      uint4 v = *(const uint4*)&tile[r][sl];
      *(uint4*)(out + (size_t)(r0 + r) * 512 + s0 + sl) = v;
    }
  }
}

// ---------------- bvo[o] = bo[o] + sum_j wo[o][j]*bv[j]  (fp32) ----------------
__global__ __launch_bounds__(256) void k_bvo(
    const float* __restrict__ wo, const float* __restrict__ bv,
    const float* __restrict__ bo, float* __restrict__ bvo) {
  const int o = blockIdx.x * 256 + threadIdx.x;
  float acc = bo[o];
  const float* row = wo + (size_t)o * 512;
  for (int j = 0; j < 512; ++j) acc += row[j] * bv[j];
  bvo[o] = acc;
}

// ---------------- u[c] = sum_o bq[o]*wk[o][c]  (fp32) ----------------
__global__ __launch_bounds__(256) void k_ub(
    const float* __restrict__ wk, const float* __restrict__ bq,
    float* __restrict__ u) {
  const int c = blockIdx.x * 256 + threadIdx.x;
  float acc = 0.f;
  for (int o = 0; o < 512; ++o) acc += bq[o] * wk[(size_t)o * 512 + c];
  u[c] = acc;
}

// ---------- K0: x fp32 [b][c][p] -> xT bf16 [pixel][c]  AND  xV bf16 [c][win*64+tok] ----------
__global__ __launch_bounds__(256) void k_transpose(
    const float* __restrict__ X, unsigned short* __restrict__ XT,
    unsigned short* __restrict__ XV) {
  __shared__ unsigned short tile[64][72];
  const int p0 = blockIdx.x << 6, c0 = blockIdx.y << 6, b = blockIdx.z;
  const float* xb = X + (size_t)b * 8388608u;
  unsigned short* xtb = XT + (size_t)b * 8388608u;
  const int t = threadIdx.x;
  const int h = p0 >> 7, th2 = h >> 3, hrow = h & 7;
  const int widb = b * 256 + th2 * 16 + ((p0 & 127) >> 3);
  {
    const int cl = t >> 3, pl = (t & 7) << 3;
    const int widx = t & 7;
#pragma unroll
    for (int pass = 0; pass < 2; ++pass) {
      const int c = cl + pass * 32;
      const float* src = xb + (size_t)(c0 + c) * 16384 + p0 + pl;
      const float4 f0 = ((const float4*)src)[0];
      const float4 f1 = ((const float4*)src)[1];
      unsigned short r8[8];
      r8[0] = f2b(f0.x); r8[1] = f2b(f0.y); r8[2] = f2b(f0.z); r8[3] = f2b(f0.w);
      r8[4] = f2b(f1.x); r8[5] = f2b(f1.y); r8[6] = f2b(f1.z); r8[7] = f2b(f1.w);
#pragma unroll
      for (int i = 0; i < 8; ++i) tile[pl + i][c] = r8[i];
      *(uint4*)(XV + (size_t)(c0 + c) * 131072 +
                (size_t)(widb + widx) * 64 + hrow * 8) = *(const uint4*)r8;
    }
  }
  __syncthreads();
  {
    const int pl = t >> 3, cl = (t & 7) << 3;
#pragma unroll
    for (int pass = 0; pass < 2; ++pass) {
      const int p = pl + pass * 32;
      uint4 v = *(const uint4*)&tile[p][cl];
      *(uint4*)(xtb + (size_t)(p0 + p) * 512 + c0 + cl) = v;
    }
  }
}

// ========== 256x256 GEMM, K=512 as 16 K-subtiles of 32, depth-3 counted pipeline ==========
// C[m][n] = sum_k A[m][k]*B[n][k] (+bias), K=512. LDS 4 buf x [256][32] A+B = 128 KiB,
// row stride 64 B (bank-uniform fragment reads). Counted vmcnt, never 0 in steady loop.
// MODE 0: T-proj. bf16 C[m=pixel][n] ldc=512, bias0[n]. grid 1024 XCD-chunked.
// MODE 2: final.  fp32 C->(B,C,H,W) from [m=chan][n=pixel], bias0[m]. grid 1024.
// MODE 3: weight-prep. bf16 C[m][n] ldc=512, no bias. grid 4.
template <int MODE>
__global__ __launch_bounds__(512, 2) void k_gemm256(
    const unsigned short* __restrict__ A, const unsigned short* __restrict__ B,
    const float* __restrict__ bias0, void* __restrict__ C0v) {
  __shared__ unsigned short lsA[4][256 * 32];
  __shared__ unsigned short lsB[4][256 * 32];
  const int bid = blockIdx.x;
  int mt, nt;
  if (MODE == 0) {
    const int work = ((bid & 7) << 7) + (bid >> 3);  // grid 1024
    mt = work >> 1; nt = work & 1;
  } else if (MODE == 2) {
    const int work = ((bid & 7) << 7) + (bid >> 3);  // grid 1024
    nt = work >> 1; mt = work & 1;
  } else {
    mt = bid & 1; nt = bid >> 1;                     // grid 4
  }
  const int m0 = mt << 8, n0 = nt << 8;

  const int t = threadIdx.x;
  const int l = t & 63;
  const int lr = l & 15, lg = l >> 4;
  const int w = t >> 6;
  const int wr = w >> 2, wc = w & 3;
  const int ra = wr << 7, rb = wc << 6;
  const int srowS = t >> 2;        // 0..127 (+128 for 2nd gload)
  const int scolS = (t & 3) << 3;  // shorts

  f32x4 acc[8][4];
#pragma unroll
  for (int i = 0; i < 8; ++i)
#pragma unroll
    for (int j = 0; j < 4; ++j) acc[i][j] = f32x4{0.f, 0.f, 0.f, 0.f};

  auto stage = [&](int kt) {
    const int buf = kt & 3, k0 = kt << 5;
#pragma unroll
    for (int hh = 0; hh < 2; ++hh) {
      gload16(A + (size_t)(m0 + srowS + hh * 128) * 512 + k0 + scolS,
              &lsA[buf][(srowS + hh * 128) * 32 + scolS]);
      gload16(B + (size_t)(n0 + srowS + hh * 128) * 512 + k0 + scolS,
              &lsB[buf][(srowS + hh * 128) * 32 + scolS]);
    }
  };
  auto compute = [&](int kt) {
    const int buf = kt & 3;
    bf16x8 af[8], bfv[4];
#pragma unroll
    for (int i = 0; i < 8; ++i)
      af[i] = *(const bf16x8*)&lsA[buf][(ra + i * 16 + lr) * 32 + lg * 8];
#pragma unroll
    for (int j = 0; j < 4; ++j)
      bfv[j] = *(const bf16x8*)&lsB[buf][(rb + j * 16 + lr) * 32 + lg * 8];
    __builtin_amdgcn_s_setprio(1);
#pragma unroll
    for (int i = 0; i < 8; ++i)
#pragma unroll
      for (int j = 0; j < 4; ++j)
        acc[i][j] = MFMA16(af[i], bfv[j], acc[i][j]);
    __builtin_amdgcn_s_setprio(0);
  };

  stage(0); stage(1); stage(2);  // depth-3 prologue

#define GITER(kt, vm)                                        \
  asm volatile("s_waitcnt vmcnt(" #vm ")" ::: "memory");     \
  __builtin_amdgcn_s_barrier();                              \
  __builtin_amdgcn_sched_barrier(0);                         \
  if ((kt) + 3 < 16) stage((kt) + 3);                        \
  compute(kt);                                               \
  __builtin_amdgcn_sched_barrier(0);                         \
  __builtin_amdgcn_s_barrier();

  GITER(0, 8)  GITER(1, 8)  GITER(2, 8)  GITER(3, 8)
  GITER(4, 8)  GITER(5, 8)  GITER(6, 8)  GITER(7, 8)
  GITER(8, 8)  GITER(9, 8)  GITER(10, 8) GITER(11, 8)
  GITER(12, 8) GITER(13, 8) GITER(14, 4) GITER(15, 0)
#undef GITER

  // ---------------- epilogue ----------------
#pragma unroll
  for (int i = 0; i < 8; ++i) {
    const int cmb = m0 + ra + i * 16 + lg * 4;
#pragma unroll
    for (int j = 0; j < 4; ++j) {
      const int cn = n0 + rb + j * 16 + lr;
      const float bn = (MODE == 0) ? bias0[cn] : 0.f;
#pragma unroll
      for (int r = 0; r < 4; ++r) {
        const int cm = cmb + r;
        if (MODE == 0) {
          ((unsigned short*)C0v)[(size_t)cm * 512 + cn] = f2b(acc[i][j][r] + bn);
        } else if (MODE == 2) {
          const float val = acc[i][j][r] + bias0[cm];
          const int bb = cn >> 14, p = cn & 16383;
          ((float*)C0v)[(size_t)bb * 8388608 + (size_t)cm * 16384 + p] = val;
        } else {
          ((unsigned short*)C0v)[(size_t)cm * 512 + cn] = f2b(acc[i][j][r]);
        }
      }
    }
  }
}

// ---------------- K2: window attention; K-side reads xT directly ----------------
// Q(=T): [pixel][c] bf16.  XT: [pixel][c] bf16.  XV: [c][win*64+tok] bf16.
// Y out: [pixel][c] bf16 (fresh buffer).
__global__ __launch_bounds__(256) void k_attn(
    const unsigned short* __restrict__ Q, const unsigned short* __restrict__ XT,
    const unsigned short* __restrict__ XV, unsigned short* __restrict__ Y) {
  __shared__ unsigned short P_lds[64][72];
  const int win = ((blockIdx.x & 7) << 8) + (blockIdx.x >> 3);
  const int b = win >> 8, th = (win >> 4) & 15, tw = win & 15;
  const size_t p_base = (size_t)b * 16384 + (size_t)th * 1024 + (size_t)tw * 8;
  const int t = threadIdx.x, w = t >> 6, l = t & 63;
  const int lr = l & 15, lg = l >> 4;
  const int qs = w << 4;
  const int qtok = qs + lr;
  const unsigned short* qrow =
      Q + (p_base + (size_t)(qtok >> 3) * 128 + (qtok & 7)) * 512;
  const unsigned short* krow =
      XT + (p_base + (size_t)(lr >> 3) * 128 + (lr & 7)) * 512;

  f32x4 acc[4];
#pragma unroll
  for (int i = 0; i < 4; ++i) acc[i] = f32x4{0.f, 0.f, 0.f, 0.f};

  for (int cs = 0; cs < 16; ++cs) {
    const int co = cs * 32 + lg * 8;
    const bf16x8 bq = *(const bf16x8*)(qrow + co);
#pragma unroll
    for (int mt = 0; mt < 4; ++mt) {
      const bf16x8 ak = *(const bf16x8*)(krow + (size_t)mt * 131072 + co);
      acc[mt] = MFMA16(ak, bq, acc[mt]);
    }
  }

  const float scale = 0.044194173824159216f;  // 1/sqrt(512)
  float pv[4][4];
  float mx = -3.0e38f;
#pragma unroll
  for (int mt = 0; mt < 4; ++mt)
#pragma unroll
    for (int j = 0; j < 4; ++j) {
      const float s = acc[mt][j] * scale;
      pv[mt][j] = s;
      mx = fmaxf(mx, s);
    }
  mx = fmaxf(mx, __shfl_xor(mx, 16));
  mx = fmaxf(mx, __shfl_xor(mx, 32));
  float sum = 0.f;
#pragma unroll
  for (int mt = 0; mt < 4; ++mt)
#pragma unroll
    for (int j = 0; j < 4; ++j) {
      const float e = __expf(pv[mt][j] - mx);
      pv[mt][j] = e;
      sum += e;
    }
  sum += __shfl_xor(sum, 16);
  sum += __shfl_xor(sum, 32);
  const float inv = 1.f / sum;

#pragma unroll
  for (int mt = 0; mt < 4; ++mt)
#pragma unroll
    for (int j = 0; j < 4; j += 2) {
      const unsigned int pk =
          (unsigned int)f2b(pv[mt][j] * inv) |
          ((unsigned int)f2b(pv[mt][j + 1] * inv) << 16);
      *(unsigned int*)&P_lds[qtok][mt * 16 + lg * 4 + j] = pk;
    }
  __syncthreads();

  const bf16x8 pa0 = *(const bf16x8*)&P_lds[qtok][lg * 8];
  const bf16x8 pa1 = *(const bf16x8*)&P_lds[qtok][32 + lg * 8];
  const unsigned short* vbase =
      XV + (size_t)lr * 131072 + (size_t)win * 64 + lg * 8;
  for (int nt = 0; nt < 32; ++nt) {
    const unsigned short* vp = vbase + (size_t)nt * (16 * 131072);
    const bf16x8 v0 = *(const bf16x8*)vp;
    const bf16x8 v1 = *(const bf16x8*)(vp + 32);
    f32x4 o = f32x4{0.f, 0.f, 0.f, 0.f};
    o = MFMA16(pa0, v0, o);
    o = MFMA16(pa1, v1, o);
#pragma unroll
    for (int r = 0; r < 4; ++r) {
      const int qq = qs + lg * 4 + r;
      const size_t p = p_base + (size_t)(qq >> 3) * 128 + (qq & 7);
      Y[p * 512 + nt * 16 + lr] = f2b(o[r]);
    }
  }
}

// ---------------- launch ----------------
extern "C" void kernel_launch(void* const* d_in, const int* in_sizes, int n_in,
                              void* d_out, int out_size, void* d_ws,
                              size_t ws_size, hipStream_t stream) {
  (void)in_sizes; (void)n_in; (void)out_size;
  const float* x = (const float*)d_in[0];
  const float* wq = (const float*)d_in[1];
  const float* bq = (const float*)d_in[2];
  const float* wk = (const float*)d_in[3];
  const float* bk = (const float*)d_in[4];  // cancels in softmax (exactly)
  const float* wv = (const float*)d_in[5];
  const float* bv = (const float*)d_in[6];
  const float* wo = (const float*)d_in[7];
  const float* bo = (const float*)d_in[8];
  (void)bk;

  // ws layout (shorts):
  // [0] wqT | [262144] wkT | [524288] wvT | [786432] wo_b | [1048576] wvo
  // [1310720] bvo fp32(512) | [1311744] u fp32(512) | [1572864] Bqk
  // [2097152] xT | xV | kws(Y)
  const size_t NEED = (size_t)(2097152 + 3 * 67108864) * 2;
  if (ws_size < NEED) return;

  unsigned short* wb = (unsigned short*)d_ws;
  unsigned short* wqT = wb;
  unsigned short* wkT = wb + 262144;
  unsigned short* wvT = wb + 524288;
  unsigned short* wo_b = wb + 786432;
  unsigned short* wvo = wb + 1048576;
  float* bvo = (float*)(wb + 1310720);
  float* ub = (float*)(wb + 1311744);
  unsigned short* Bqk = wb + 1572864;
  unsigned short* xT = wb + 2097152;    // [pixel][c]
  unsigned short* xV = xT + 67108864;   // [c][win*64+tok]
  unsigned short* Ybuf = xV + 67108864; // attn output
  unsigned short* Tq = (unsigned short*)d_out;  // T staged (bf16), fully
                                                // overwritten by MODE 2 fp32

  k_wtrans<<<dim3(8, 8), 256, 0, stream>>>(wq, wqT);
  k_wtrans<<<dim3(8, 8), 256, 0, stream>>>(wk, wkT);
  k_wtrans<<<dim3(8, 8), 256, 0, stream>>>(wv, wvT);
  k_wconv<<<256, 256, 0, stream>>>(wo, wo_b);
  k_gemm256<3><<<4, 512, 0, stream>>>(wkT, wqT, nullptr, Bqk);   // Bqk[j][c]
  k_gemm256<3><<<4, 512, 0, stream>>>(wo_b, wvT, nullptr, wvo);  // Wvo = Wo*Wv
  k_ub<<<2, 256, 0, stream>>>(wk, bq, ub);
  k_bvo<<<2, 256, 0, stream>>>(wo, bv, bo, bvo);
  k_transpose<<<dim3(256, 8, 8), 256, 0, stream>>>(x, xT, xV);
  k_gemm256<0><<<1024, 512, 0, stream>>>(xT, Bqk, ub, Tq);       // T = X*Bqk^T + u
  k_attn<<<2048, 256, 0, stream>>>(Tq, xT, xV, Ybuf);
  k_gemm256<2><<<1024, 512, 0, stream>>>(wvo, Ybuf, bvo, d_out);
}

// Round 10
// 694.908 us; speedup vs baseline: 1.3318x; 1.0347x over previous
//
#include <hip/hip_runtime.h>

typedef __attribute__((ext_vector_type(8))) short bf16x8;
typedef __attribute__((ext_vector_type(4))) float f32x4;

#define MFMA16(a, b, c) __builtin_amdgcn_mfma_f32_16x16x32_bf16((a), (b), (c), 0, 0, 0)

__device__ __forceinline__ float b2f(unsigned short u) {
  unsigned int v = ((unsigned int)u) << 16;
  return __builtin_bit_cast(float, v);
}
__device__ __forceinline__ unsigned short f2b(float f) {
  unsigned int u = __builtin_bit_cast(unsigned int, f);
  u += 0x7fffu + ((u >> 16) & 1u);
  return (unsigned short)(u >> 16);
}
__device__ __forceinline__ void gload16(const void* g, void* l) {
  __builtin_amdgcn_global_load_lds(
      (const __attribute__((address_space(1))) unsigned int*)g,
      (__attribute__((address_space(3))) unsigned int*)l, 16, 0, 0);
}

// ---------------- wo fp32 -> bf16, layout preserved [o][c] ----------------
__global__ __launch_bounds__(256) void k_wconv(
    const float* __restrict__ src, unsigned short* __restrict__ dst) {
  const int i = (blockIdx.x * 256 + threadIdx.x) * 4;
  const float4 v = *(const float4*)(src + i);
  uint2 p;
  p.x = (unsigned int)f2b(v.x) | ((unsigned int)f2b(v.y) << 16);
  p.y = (unsigned int)f2b(v.z) | ((unsigned int)f2b(v.w) << 16);
  *(uint2*)(dst + i) = p;
}

// ---------------- w fp32 [a][b] -> bf16 [b][a] (512x512) ----------------
__global__ __launch_bounds__(256) void k_wtrans(
    const float* __restrict__ in, unsigned short* __restrict__ out) {
  __shared__ unsigned short tile[64][72];
  const int r0 = blockIdx.x << 6, s0 = blockIdx.y << 6;
  const int t = threadIdx.x;
  {
    const int sl = t >> 3, rl = (t & 7) << 3;
#pragma unroll
    for (int pass = 0; pass < 2; ++pass) {
      const int s = sl + pass * 32;
      const float* src = in + (size_t)(s0 + s) * 512 + r0 + rl;
      const float4 f0 = ((const float4*)src)[0];
      const float4 f1 = ((const float4*)src)[1];
      tile[rl + 0][s] = f2b(f0.x);
      tile[rl + 1][s] = f2b(f0.y);
      tile[rl + 2][s] = f2b(f0.z);
      tile[rl + 3][s] = f2b(f0.w);
      tile[rl + 4][s] = f2b(f1.x);
      tile[rl + 5][s] = f2b(f1.y);
      tile[rl + 6][s] = f2b(f1.z);
      tile[rl + 7][s] = f2b(f1.w);
    }
  }
  __syncthreads();
  {
    const int rl = t >> 3, sl = (t & 7) << 3;
#pragma unroll
    for (int pass = 0; pass < 2; ++pass) {
      const int r = rl + pass * 32;
      uint4 v = *(const uint4*)&tile[r][sl];
      *(uint4*)(out + (size_t)(r0 + r) * 512 + s0 + sl) = v;
    }
  }
}

// ---------------- bvo[o] = bo[o] + sum_j wo[o][j]*bv[j]  (fp32) ----------------
__global__ __launch_bounds__(256) void k_bvo(
    const float* __restrict__ wo, const float* __restrict__ bv,
    const float* __restrict__ bo, float* __restrict__ bvo) {
  const int o = blockIdx.x * 256 + threadIdx.x;
  float acc = bo[o];
  const float* row = wo + (size_t)o * 512;
  for (int j = 0; j < 512; ++j) acc += row[j] * bv[j];
  bvo[o] = acc;
}

// ---------------- u[c] = sum_o bq[o]*wk[o][c]  (fp32) ----------------
__global__ __launch_bounds__(256) void k_ub(
    const float* __restrict__ wk, const float* __restrict__ bq,
    float* __restrict__ u) {
  const int c = blockIdx.x * 256 + threadIdx.x;
  float acc = 0.f;
  for (int o = 0; o < 512; ++o) acc += bq[o] * wk[(size_t)o * 512 + c];
  u[c] = acc;
}

// ---------- K0: x fp32 [b][c][p] -> xT bf16 [pixel][c]  AND  xV bf16 [c][win*64+tok] ----------
__global__ __launch_bounds__(256) void k_transpose(
    const float* __restrict__ X, unsigned short* __restrict__ XT,
    unsigned short* __restrict__ XV) {
  __shared__ unsigned short tile[64][72];
  const int p0 = blockIdx.x << 6, c0 = blockIdx.y << 6, b = blockIdx.z;
  const float* xb = X + (size_t)b * 8388608u;
  unsigned short* xtb = XT + (size_t)b * 8388608u;
  const int t = threadIdx.x;
  const int h = p0 >> 7, th2 = h >> 3, hrow = h & 7;
  const int widb = b * 256 + th2 * 16 + ((p0 & 127) >> 3);
  {
    const int cl = t >> 3, pl = (t & 7) << 3;
    const int widx = t & 7;
#pragma unroll
    for (int pass = 0; pass < 2; ++pass) {
      const int c = cl + pass * 32;
      const float* src = xb + (size_t)(c0 + c) * 16384 + p0 + pl;
      const float4 f0 = ((const float4*)src)[0];
      const float4 f1 = ((const float4*)src)[1];
      unsigned short r8[8];
      r8[0] = f2b(f0.x); r8[1] = f2b(f0.y); r8[2] = f2b(f0.z); r8[3] = f2b(f0.w);
      r8[4] = f2b(f1.x); r8[5] = f2b(f1.y); r8[6] = f2b(f1.z); r8[7] = f2b(f1.w);
#pragma unroll
      for (int i = 0; i < 8; ++i) tile[pl + i][c] = r8[i];
      *(uint4*)(XV + (size_t)(c0 + c) * 131072 +
                (size_t)(widb + widx) * 64 + hrow * 8) = *(const uint4*)r8;
    }
  }
  __syncthreads();
  {
    const int pl = t >> 3, cl = (t & 7) << 3;
#pragma unroll
    for (int pass = 0; pass < 2; ++pass) {
      const int p = pl + pass * 32;
      uint4 v = *(const uint4*)&tile[p][cl];
      *(uint4*)(xtb + (size_t)(p0 + p) * 512 + c0 + cl) = v;
    }
  }
}

// ========== 256x256 GEMM, K=512 as 16 K-subtiles of 32, depth-3 counted pipeline ==========
template <int MODE>
__global__ __launch_bounds__(512, 2) void k_gemm256(
    const unsigned short* __restrict__ A, const unsigned short* __restrict__ B,
    const float* __restrict__ bias0, void* __restrict__ C0v) {
  __shared__ unsigned short lsA[4][256 * 32];
  __shared__ unsigned short lsB[4][256 * 32];
  const int bid = blockIdx.x;
  int mt, nt;
  if (MODE == 0) {
    const int work = ((bid & 7) << 7) + (bid >> 3);  // grid 1024
    mt = work >> 1; nt = work & 1;
  } else if (MODE == 2) {
    const int work = ((bid & 7) << 7) + (bid >> 3);  // grid 1024
    nt = work >> 1; mt = work & 1;
  } else {
    mt = bid & 1; nt = bid >> 1;                     // grid 4
  }
  const int m0 = mt << 8, n0 = nt << 8;

  const int t = threadIdx.x;
  const int l = t & 63;
  const int lr = l & 15, lg = l >> 4;
  const int w = t >> 6;
  const int wr = w >> 2, wc = w & 3;
  const int ra = wr << 7, rb = wc << 6;
  const int srowS = t >> 2;
  const int scolS = (t & 3) << 3;

  f32x4 acc[8][4];
#pragma unroll
  for (int i = 0; i < 8; ++i)
#pragma unroll
    for (int j = 0; j < 4; ++j) acc[i][j] = f32x4{0.f, 0.f, 0.f, 0.f};

  auto stage = [&](int kt) {
    const int buf = kt & 3, k0 = kt << 5;
#pragma unroll
    for (int hh = 0; hh < 2; ++hh) {
      gload16(A + (size_t)(m0 + srowS + hh * 128) * 512 + k0 + scolS,
              &lsA[buf][(srowS + hh * 128) * 32 + scolS]);
      gload16(B + (size_t)(n0 + srowS + hh * 128) * 512 + k0 + scolS,
              &lsB[buf][(srowS + hh * 128) * 32 + scolS]);
    }
  };
  auto compute = [&](int kt) {
    const int buf = kt & 3;
    bf16x8 af[8], bfv[4];
#pragma unroll
    for (int i = 0; i < 8; ++i)
      af[i] = *(const bf16x8*)&lsA[buf][(ra + i * 16 + lr) * 32 + lg * 8];
#pragma unroll
    for (int j = 0; j < 4; ++j)
      bfv[j] = *(const bf16x8*)&lsB[buf][(rb + j * 16 + lr) * 32 + lg * 8];
    __builtin_amdgcn_s_setprio(1);
#pragma unroll
    for (int i = 0; i < 8; ++i)
#pragma unroll
      for (int j = 0; j < 4; ++j)
        acc[i][j] = MFMA16(af[i], bfv[j], acc[i][j]);
    __builtin_amdgcn_s_setprio(0);
  };

  stage(0); stage(1); stage(2);

#define GITER(kt, vm)                                        \
  asm volatile("s_waitcnt vmcnt(" #vm ")" ::: "memory");     \
  __builtin_amdgcn_s_barrier();                              \
  __builtin_amdgcn_sched_barrier(0);                         \
  if ((kt) + 3 < 16) stage((kt) + 3);                        \
  compute(kt);                                               \
  __builtin_amdgcn_sched_barrier(0);                         \
  __builtin_amdgcn_s_barrier();

  GITER(0, 8)  GITER(1, 8)  GITER(2, 8)  GITER(3, 8)
  GITER(4, 8)  GITER(5, 8)  GITER(6, 8)  GITER(7, 8)
  GITER(8, 8)  GITER(9, 8)  GITER(10, 8) GITER(11, 8)
  GITER(12, 8) GITER(13, 8) GITER(14, 4) GITER(15, 0)
#undef GITER

#pragma unroll
  for (int i = 0; i < 8; ++i) {
    const int cmb = m0 + ra + i * 16 + lg * 4;
#pragma unroll
    for (int j = 0; j < 4; ++j) {
      const int cn = n0 + rb + j * 16 + lr;
      const float bn = (MODE == 0) ? bias0[cn] : 0.f;
#pragma unroll
      for (int r = 0; r < 4; ++r) {
        const int cm = cmb + r;
        if (MODE == 0) {
          ((unsigned short*)C0v)[(size_t)cm * 512 + cn] = f2b(acc[i][j][r] + bn);
        } else if (MODE == 2) {
          const float val = acc[i][j][r] + bias0[cm];
          const int bb = cn >> 14, p = cn & 16383;
          ((float*)C0v)[(size_t)bb * 8388608 + (size_t)cm * 16384 + p] = val;
        } else {
          ((unsigned short*)C0v)[(size_t)cm * 512 + cn] = f2b(acc[i][j][r]);
        }
      }
    }
  }
}

// ---------------- K2: window attention, depth-2 register-pipelined ----------------
// Q(=T): [pixel][c] bf16.  XT: [pixel][c] bf16 (K-side).  XV: [c][win*64+tok] bf16.
// Y out: [pixel][c] bf16.
__global__ __launch_bounds__(256) void k_attn(
    const unsigned short* __restrict__ Q, const unsigned short* __restrict__ XT,
    const unsigned short* __restrict__ XV, unsigned short* __restrict__ Y) {
  __shared__ unsigned short P_lds[64][72];
  const int win = ((blockIdx.x & 7) << 8) + (blockIdx.x >> 3);
  const int b = win >> 8, th = (win >> 4) & 15, tw = win & 15;
  const size_t p_base = (size_t)b * 16384 + (size_t)th * 1024 + (size_t)tw * 8;
  const int t = threadIdx.x, w = t >> 6, l = t & 63;
  const int lr = l & 15, lg = l >> 4;
  const int qs = w << 4;
  const int qtok = qs + lr;
  const unsigned short* qrow =
      Q + (p_base + (size_t)(qtok >> 3) * 128 + (qtok & 7)) * 512;
  const unsigned short* krow =
      XT + (p_base + (size_t)(lr >> 3) * 128 + (lr & 7)) * 512;

  f32x4 acc[4];
#pragma unroll
  for (int i = 0; i < 4; ++i) acc[i] = f32x4{0.f, 0.f, 0.f, 0.f};

  // ---- QK^T, depth-2 register pipeline (loads issued 2 iters ahead) ----
  bf16x8 bqp[2], akp[2][4];
#pragma unroll
  for (int pp = 0; pp < 2; ++pp) {
    const int co = pp * 32 + lg * 8;
    bqp[pp] = *(const bf16x8*)(qrow + co);
#pragma unroll
    for (int mt = 0; mt < 4; ++mt)
      akp[pp][mt] = *(const bf16x8*)(krow + (size_t)mt * 131072 + co);
  }
#pragma unroll
  for (int cs = 0; cs < 16; ++cs) {
    const int cb = cs & 1;
    bf16x8 bqn;
    bf16x8 akn[4];
    if (cs + 2 < 16) {
      const int co = (cs + 2) * 32 + lg * 8;
      bqn = *(const bf16x8*)(qrow + co);
#pragma unroll
      for (int mt = 0; mt < 4; ++mt)
        akn[mt] = *(const bf16x8*)(krow + (size_t)mt * 131072 + co);
    }
    __builtin_amdgcn_s_setprio(1);
#pragma unroll
    for (int mt = 0; mt < 4; ++mt)
      acc[mt] = MFMA16(akp[cb][mt], bqp[cb], acc[mt]);
    __builtin_amdgcn_s_setprio(0);
    if (cs + 2 < 16) {
      bqp[cb] = bqn;
#pragma unroll
      for (int mt = 0; mt < 4; ++mt) akp[cb][mt] = akn[mt];
    }
  }

  const float scale = 0.044194173824159216f;  // 1/sqrt(512)
  float pv[4][4];
  float mx = -3.0e38f;
#pragma unroll
  for (int mt = 0; mt < 4; ++mt)
#pragma unroll
    for (int j = 0; j < 4; ++j) {
      const float s = acc[mt][j] * scale;
      pv[mt][j] = s;
      mx = fmaxf(mx, s);
    }
  mx = fmaxf(mx, __shfl_xor(mx, 16));
  mx = fmaxf(mx, __shfl_xor(mx, 32));
  float sum = 0.f;
#pragma unroll
  for (int mt = 0; mt < 4; ++mt)
#pragma unroll
    for (int j = 0; j < 4; ++j) {
      const float e = __expf(pv[mt][j] - mx);
      pv[mt][j] = e;
      sum += e;
    }
  sum += __shfl_xor(sum, 16);
  sum += __shfl_xor(sum, 32);
  const float inv = 1.f / sum;

#pragma unroll
  for (int mt = 0; mt < 4; ++mt)
#pragma unroll
    for (int j = 0; j < 4; j += 2) {
      const unsigned int pk =
          (unsigned int)f2b(pv[mt][j] * inv) |
          ((unsigned int)f2b(pv[mt][j + 1] * inv) << 16);
      *(unsigned int*)&P_lds[qtok][mt * 16 + lg * 4 + j] = pk;
    }
  __syncthreads();

  // ---- PV, depth-2 register pipeline; hoisted store bases ----
  const bf16x8 pa0 = *(const bf16x8*)&P_lds[qtok][lg * 8];
  const bf16x8 pa1 = *(const bf16x8*)&P_lds[qtok][32 + lg * 8];
  const unsigned short* vbase =
      XV + (size_t)lr * 131072 + (size_t)win * 64 + lg * 8;
  unsigned short* ybase[4];
#pragma unroll
  for (int r = 0; r < 4; ++r) {
    const int qq = qs + lg * 4 + r;
    ybase[r] =
        Y + (p_base + (size_t)(qq >> 3) * 128 + (qq & 7)) * 512 + lr;
  }
  bf16x8 v0p[2], v1p[2];
#pragma unroll
  for (int pp = 0; pp < 2; ++pp) {
    const unsigned short* vp = vbase + (size_t)pp * (16 * 131072);
    v0p[pp] = *(const bf16x8*)vp;
    v1p[pp] = *(const bf16x8*)(vp + 32);
  }
#pragma unroll
  for (int nt = 0; nt < 32; ++nt) {
    const int cb = nt & 1;
    bf16x8 v0n, v1n;
    if (nt + 2 < 32) {
      const unsigned short* vp = vbase + (size_t)(nt + 2) * (16 * 131072);
      v0n = *(const bf16x8*)vp;
      v1n = *(const bf16x8*)(vp + 32);
    }
    f32x4 o = f32x4{0.f, 0.f, 0.f, 0.f};
    __builtin_amdgcn_s_setprio(1);
    o = MFMA16(pa0, v0p[cb], o);
    o = MFMA16(pa1, v1p[cb], o);
    __builtin_amdgcn_s_setprio(0);
#pragma unroll
    for (int r = 0; r < 4; ++r) ybase[r][nt * 16] = f2b(o[r]);
    if (nt + 2 < 32) {
      v0p[cb] = v0n;
      v1p[cb] = v1n;
    }
  }
}

// ---------------- launch ----------------
extern "C" void kernel_launch(void* const* d_in, const int* in_sizes, int n_in,
                              void* d_out, int out_size, void* d_ws,
                              size_t ws_size, hipStream_t stream) {
  (void)in_sizes; (void)n_in; (void)out_size;
  const float* x = (const float*)d_in[0];
  const float* wq = (const float*)d_in[1];
  const float* bq = (const float*)d_in[2];
  const float* wk = (const float*)d_in[3];
  const float* bk = (const float*)d_in[4];  // cancels in softmax (exactly)
  const float* wv = (const float*)d_in[5];
  const float* bv = (const float*)d_in[6];
  const float* wo = (const float*)d_in[7];
  const float* bo = (const float*)d_in[8];
  (void)bk;

  const size_t NEED = (size_t)(2097152 + 3 * 67108864) * 2;
  if (ws_size < NEED) return;

  unsigned short* wb = (unsigned short*)d_ws;
  unsigned short* wqT = wb;
  unsigned short* wkT = wb + 262144;
  unsigned short* wvT = wb + 524288;
  unsigned short* wo_b = wb + 786432;
  unsigned short* wvo = wb + 1048576;
  float* bvo = (float*)(wb + 1310720);
  float* ub = (float*)(wb + 1311744);
  unsigned short* Bqk = wb + 1572864;
  unsigned short* xT = wb + 2097152;    // [pixel][c]
  unsigned short* xV = xT + 67108864;   // [c][win*64+tok]
  unsigned short* Ybuf = xV + 67108864; // attn output
  unsigned short* Tq = (unsigned short*)d_out;  // T staged (bf16), fully
                                                // overwritten by MODE 2 fp32

  k_wtrans<<<dim3(8, 8), 256, 0, stream>>>(wq, wqT);
  k_wtrans<<<dim3(8, 8), 256, 0, stream>>>(wk, wkT);
  k_wtrans<<<dim3(8, 8), 256, 0, stream>>>(wv, wvT);
  k_wconv<<<256, 256, 0, stream>>>(wo, wo_b);
  k_gemm256<3><<<4, 512, 0, stream>>>(wkT, wqT, nullptr, Bqk);   // Bqk[j][c]
  k_gemm256<3><<<4, 512, 0, stream>>>(wo_b, wvT, nullptr, wvo);  // Wvo = Wo*Wv
  k_ub<<<2, 256, 0, stream>>>(wk, bq, ub);
  k_bvo<<<2, 256, 0, stream>>>(wo, bv, bo, bvo);
  k_transpose<<<dim3(256, 8, 8), 256, 0, stream>>>(x, xT, xV);
  k_gemm256<0><<<1024, 512, 0, stream>>>(xT, Bqk, ub, Tq);       // T = X*Bqk^T + u
  k_attn<<<2048, 256, 0, stream>>>(Tq, xT, xV, Ybuf);
  k_gemm256<2><<<1024, 512, 0, stream>>>(wvo, Ybuf, bvo, d_out);
}

// Round 11
// 637.684 us; speedup vs baseline: 1.4513x; 1.0897x over previous
//
#include <hip/hip_runtime.h>

typedef __attribute__((ext_vector_type(8))) short bf16x8;
typedef __attribute__((ext_vector_type(4))) float f32x4;

#define MFMA16(a, b, c) __builtin_amdgcn_mfma_f32_16x16x32_bf16((a), (b), (c), 0, 0, 0)

__device__ __forceinline__ float b2f(unsigned short u) {
  unsigned int v = ((unsigned int)u) << 16;
  return __builtin_bit_cast(float, v);
}
__device__ __forceinline__ unsigned short f2b(float f) {
  unsigned int u = __builtin_bit_cast(unsigned int, f);
  u += 0x7fffu + ((u >> 16) & 1u);
  return (unsigned short)(u >> 16);
}
__device__ __forceinline__ void gload16(const void* g, void* l) {
  __builtin_amdgcn_global_load_lds(
      (const __attribute__((address_space(1))) unsigned int*)g,
      (__attribute__((address_space(3))) unsigned int*)l, 16, 0, 0);
}

// ---------------- wo fp32 -> bf16, layout preserved [o][c] ----------------
__global__ __launch_bounds__(256) void k_wconv(
    const float* __restrict__ src, unsigned short* __restrict__ dst) {
  const int i = (blockIdx.x * 256 + threadIdx.x) * 4;
  const float4 v = *(const float4*)(src + i);
  uint2 p;
  p.x = (unsigned int)f2b(v.x) | ((unsigned int)f2b(v.y) << 16);
  p.y = (unsigned int)f2b(v.z) | ((unsigned int)f2b(v.w) << 16);
  *(uint2*)(dst + i) = p;
}

// ---------------- w fp32 [a][b] -> bf16 [b][a] (512x512) ----------------
__global__ __launch_bounds__(256) void k_wtrans(
    const float* __restrict__ in, unsigned short* __restrict__ out) {
  __shared__ unsigned short tile[64][72];
  const int r0 = blockIdx.x << 6, s0 = blockIdx.y << 6;
  const int t = threadIdx.x;
  {
    const int sl = t >> 3, rl = (t & 7) << 3;
#pragma unroll
    for (int pass = 0; pass < 2; ++pass) {
      const int s = sl + pass * 32;
      const float* src = in + (size_t)(s0 + s) * 512 + r0 + rl;
      const float4 f0 = ((const float4*)src)[0];
      const float4 f1 = ((const float4*)src)[1];
      tile[rl + 0][s] = f2b(f0.x);
      tile[rl + 1][s] = f2b(f0.y);
      tile[rl + 2][s] = f2b(f0.z);
      tile[rl + 3][s] = f2b(f0.w);
      tile[rl + 4][s] = f2b(f1.x);
      tile[rl + 5][s] = f2b(f1.y);
      tile[rl + 6][s] = f2b(f1.z);
      tile[rl + 7][s] = f2b(f1.w);
    }
  }
  __syncthreads();
  {
    const int rl = t >> 3, sl = (t & 7) << 3;
#pragma unroll
    for (int pass = 0; pass < 2; ++pass) {
      const int r = rl + pass * 32;
      uint4 v = *(const uint4*)&tile[r][sl];
      *(uint4*)(out + (size_t)(r0 + r) * 512 + s0 + sl) = v;
    }
  }
}

// ---------------- bvo[o] = bo[o] + sum_j wo[o][j]*bv[j]  (fp32) ----------------
__global__ __launch_bounds__(256) void k_bvo(
    const float* __restrict__ wo, const float* __restrict__ bv,
    const float* __restrict__ bo, float* __restrict__ bvo) {
  const int o = blockIdx.x * 256 + threadIdx.x;
  float acc = bo[o];
  const float* row = wo + (size_t)o * 512;
  for (int j = 0; j < 512; ++j) acc += row[j] * bv[j];
  bvo[o] = acc;
}

// ---------------- u[c] = sum_o bq[o]*wk[o][c]  (fp32) ----------------
__global__ __launch_bounds__(256) void k_ub(
    const float* __restrict__ wk, const float* __restrict__ bq,
    float* __restrict__ u) {
  const int c = blockIdx.x * 256 + threadIdx.x;
  float acc = 0.f;
  for (int o = 0; o < 512; ++o) acc += bq[o] * wk[(size_t)o * 512 + c];
  u[c] = acc;
}

// ---- K0: x fp32 [b][c][h*128+w] -> xT bf16 [pixel][c] AND xV bf16 [c][win*64+tok] ----
// Block owns COMPLETE windows: (b, 32 channels, 8 h-rows = one window row, 8 windows).
// xV lines are produced whole by a single thread (no cross-block RMW); xT lines are
// produced whole by a single lane (4x16B contiguous).
__global__ __launch_bounds__(256) void k_transpose(
    const float* __restrict__ X, unsigned short* __restrict__ XT,
    unsigned short* __restrict__ XV) {
  __shared__ unsigned short tile[32][528];  // [c][local-pixel], +16 pad
  const int bx = blockIdx.x;                // 0..31
  const int wt = bx & 1, ht = bx >> 1;      // w-tile, h-tile(window row)
  const int c0 = blockIdx.y << 5;           // 32-channel tile
  const int b = blockIdx.z;
  const int w0 = wt << 6, h0 = ht << 3;
  const int t = threadIdx.x;
  const int cl = t >> 3, wl = t & 7;        // channel lane, window lane

  const float* xsrc = X + (size_t)b * 8388608u + (size_t)(c0 + cl) * 16384 +
                      (size_t)h0 * 128 + w0 + wl * 8;
  const int winb = b * 256 + ht * 16 + wt * 8;
  unsigned short* xvdst =
      XV + (size_t)(c0 + cl) * 131072 + (size_t)(winb + wl) * 64;

#pragma unroll
  for (int hh = 0; hh < 8; ++hh) {
    const float4 f0 = ((const float4*)(xsrc + hh * 128))[0];
    const float4 f1 = ((const float4*)(xsrc + hh * 128))[1];
    unsigned short r8[8];
    r8[0] = f2b(f0.x); r8[1] = f2b(f0.y); r8[2] = f2b(f0.z); r8[3] = f2b(f0.w);
    r8[4] = f2b(f1.x); r8[5] = f2b(f1.y); r8[6] = f2b(f1.z); r8[7] = f2b(f1.w);
    *(uint4*)&tile[cl][hh * 64 + wl * 8] = *(const uint4*)r8;  // 2-way bank, free
    *(uint4*)(xvdst + hh * 8) = *(const uint4*)r8;  // tok = hh*8..+7, consecutive
  }
  __syncthreads();

  // xT: each thread emits 2 pixels x 32 channels = one full 64B line per pixel
  unsigned short* xtb = XT + (size_t)b * 8388608u;
#pragma unroll
  for (int pp = 0; pp < 2; ++pp) {
    const int pl = t + pp * 256;            // local pixel 0..511
    const int hh = pl >> 6, ww = pl & 63;
    unsigned short buf[32];
#pragma unroll
    for (int c = 0; c < 32; ++c) buf[c] = tile[c][pl];  // same-dword pairs, free
    unsigned short* dst =
        xtb + ((size_t)(h0 + hh) * 128 + w0 + ww) * 512 + c0;
    *(uint4*)(dst + 0) = *(const uint4*)&buf[0];
    *(uint4*)(dst + 8) = *(const uint4*)&buf[8];
    *(uint4*)(dst + 16) = *(const uint4*)&buf[16];
    *(uint4*)(dst + 24) = *(const uint4*)&buf[24];
  }
}

// ========== 256x256 GEMM, K=512 as 16 K-subtiles of 32, depth-3 counted pipeline ==========
template <int MODE>
__global__ __launch_bounds__(512, 2) void k_gemm256(
    const unsigned short* __restrict__ A, const unsigned short* __restrict__ B,
    const float* __restrict__ bias0, void* __restrict__ C0v) {
  __shared__ unsigned short lsA[4][256 * 32];
  __shared__ unsigned short lsB[4][256 * 32];
  const int bid = blockIdx.x;
  int mt, nt;
  if (MODE == 0) {
    const int work = ((bid & 7) << 7) + (bid >> 3);  // grid 1024
    mt = work >> 1; nt = work & 1;
  } else if (MODE == 2) {
    const int work = ((bid & 7) << 7) + (bid >> 3);  // grid 1024
    nt = work >> 1; mt = work & 1;
  } else {
    mt = bid & 1; nt = bid >> 1;                     // grid 4
  }
  const int m0 = mt << 8, n0 = nt << 8;

  const int t = threadIdx.x;
  const int l = t & 63;
  const int lr = l & 15, lg = l >> 4;
  const int w = t >> 6;
  const int wr = w >> 2, wc = w & 3;
  const int ra = wr << 7, rb = wc << 6;
  const int srowS = t >> 2;
  const int scolS = (t & 3) << 3;

  f32x4 acc[8][4];
#pragma unroll
  for (int i = 0; i < 8; ++i)
#pragma unroll
    for (int j = 0; j < 4; ++j) acc[i][j] = f32x4{0.f, 0.f, 0.f, 0.f};

  auto stage = [&](int kt) {
    const int buf = kt & 3, k0 = kt << 5;
#pragma unroll
    for (int hh = 0; hh < 2; ++hh) {
      gload16(A + (size_t)(m0 + srowS + hh * 128) * 512 + k0 + scolS,
              &lsA[buf][(srowS + hh * 128) * 32 + scolS]);
      gload16(B + (size_t)(n0 + srowS + hh * 128) * 512 + k0 + scolS,
              &lsB[buf][(srowS + hh * 128) * 32 + scolS]);
    }
  };
  auto compute = [&](int kt) {
    const int buf = kt & 3;
    bf16x8 af[8], bfv[4];
#pragma unroll
    for (int i = 0; i < 8; ++i)
      af[i] = *(const bf16x8*)&lsA[buf][(ra + i * 16 + lr) * 32 + lg * 8];
#pragma unroll
    for (int j = 0; j < 4; ++j)
      bfv[j] = *(const bf16x8*)&lsB[buf][(rb + j * 16 + lr) * 32 + lg * 8];
    __builtin_amdgcn_s_setprio(1);
#pragma unroll
    for (int i = 0; i < 8; ++i)
#pragma unroll
      for (int j = 0; j < 4; ++j)
        acc[i][j] = MFMA16(af[i], bfv[j], acc[i][j]);
    __builtin_amdgcn_s_setprio(0);
  };

  stage(0); stage(1); stage(2);

#define GITER(kt, vm)                                        \
  asm volatile("s_waitcnt vmcnt(" #vm ")" ::: "memory");     \
  __builtin_amdgcn_s_barrier();                              \
  __builtin_amdgcn_sched_barrier(0);                         \
  if ((kt) + 3 < 16) stage((kt) + 3);                        \
  compute(kt);                                               \
  __builtin_amdgcn_sched_barrier(0);                         \
  __builtin_amdgcn_s_barrier();

  GITER(0, 8)  GITER(1, 8)  GITER(2, 8)  GITER(3, 8)
  GITER(4, 8)  GITER(5, 8)  GITER(6, 8)  GITER(7, 8)
  GITER(8, 8)  GITER(9, 8)  GITER(10, 8) GITER(11, 8)
  GITER(12, 8) GITER(13, 8) GITER(14, 4) GITER(15, 0)
#undef GITER

#pragma unroll
  for (int i = 0; i < 8; ++i) {
    const int cmb = m0 + ra + i * 16 + lg * 4;
#pragma unroll
    for (int j = 0; j < 4; ++j) {
      const int cn = n0 + rb + j * 16 + lr;
      const float bn = (MODE == 0) ? bias0[cn] : 0.f;
#pragma unroll
      for (int r = 0; r < 4; ++r) {
        const int cm = cmb + r;
        if (MODE == 0) {
          ((unsigned short*)C0v)[(size_t)cm * 512 + cn] = f2b(acc[i][j][r] + bn);
        } else if (MODE == 2) {
          const float val = acc[i][j][r] + bias0[cm];
          const int bb = cn >> 14, p = cn & 16383;
          ((float*)C0v)[(size_t)bb * 8388608 + (size_t)cm * 16384 + p] = val;
        } else {
          ((unsigned short*)C0v)[(size_t)cm * 512 + cn] = f2b(acc[i][j][r]);
        }
      }
    }
  }
}

// ---------------- K2: window attention, depth-2 register-pipelined ----------------
__global__ __launch_bounds__(256) void k_attn(
    const unsigned short* __restrict__ Q, const unsigned short* __restrict__ XT,
    const unsigned short* __restrict__ XV, unsigned short* __restrict__ Y) {
  __shared__ unsigned short P_lds[64][72];
  const int win = ((blockIdx.x & 7) << 8) + (blockIdx.x >> 3);
  const int b = win >> 8, th = (win >> 4) & 15, tw = win & 15;
  const size_t p_base = (size_t)b * 16384 + (size_t)th * 1024 + (size_t)tw * 8;
  const int t = threadIdx.x, w = t >> 6, l = t & 63;
  const int lr = l & 15, lg = l >> 4;
  const int qs = w << 4;
  const int qtok = qs + lr;
  const unsigned short* qrow =
      Q + (p_base + (size_t)(qtok >> 3) * 128 + (qtok & 7)) * 512;
  const unsigned short* krow =
      XT + (p_base + (size_t)(lr >> 3) * 128 + (lr & 7)) * 512;

  f32x4 acc[4];
#pragma unroll
  for (int i = 0; i < 4; ++i) acc[i] = f32x4{0.f, 0.f, 0.f, 0.f};

  bf16x8 bqp[2], akp[2][4];
#pragma unroll
  for (int pp = 0; pp < 2; ++pp) {
    const int co = pp * 32 + lg * 8;
    bqp[pp] = *(const bf16x8*)(qrow + co);
#pragma unroll
    for (int mt = 0; mt < 4; ++mt)
      akp[pp][mt] = *(const bf16x8*)(krow + (size_t)mt * 131072 + co);
  }
#pragma unroll
  for (int cs = 0; cs < 16; ++cs) {
    const int cb = cs & 1;
    bf16x8 bqn;
    bf16x8 akn[4];
    if (cs + 2 < 16) {
      const int co = (cs + 2) * 32 + lg * 8;
      bqn = *(const bf16x8*)(qrow + co);
#pragma unroll
      for (int mt = 0; mt < 4; ++mt)
        akn[mt] = *(const bf16x8*)(krow + (size_t)mt * 131072 + co);
    }
    __builtin_amdgcn_s_setprio(1);
#pragma unroll
    for (int mt = 0; mt < 4; ++mt)
      acc[mt] = MFMA16(akp[cb][mt], bqp[cb], acc[mt]);
    __builtin_amdgcn_s_setprio(0);
    if (cs + 2 < 16) {
      bqp[cb] = bqn;
#pragma unroll
      for (int mt = 0; mt < 4; ++mt) akp[cb][mt] = akn[mt];
    }
  }

  const float scale = 0.044194173824159216f;  // 1/sqrt(512)
  float pv[4][4];
  float mx = -3.0e38f;
#pragma unroll
  for (int mt = 0; mt < 4; ++mt)
#pragma unroll
    for (int j = 0; j < 4; ++j) {
      const float s = acc[mt][j] * scale;
      pv[mt][j] = s;
      mx = fmaxf(mx, s);
    }
  mx = fmaxf(mx, __shfl_xor(mx, 16));
  mx = fmaxf(mx, __shfl_xor(mx, 32));
  float sum = 0.f;
#pragma unroll
  for (int mt = 0; mt < 4; ++mt)
#pragma unroll
    for (int j = 0; j < 4; ++j) {
      const float e = __expf(pv[mt][j] - mx);
      pv[mt][j] = e;
      sum += e;
    }
  sum += __shfl_xor(sum, 16);
  sum += __shfl_xor(sum, 32);
  const float inv = 1.f / sum;

#pragma unroll
  for (int mt = 0; mt < 4; ++mt)
#pragma unroll
    for (int j = 0; j < 4; j += 2) {
      const unsigned int pk =
          (unsigned int)f2b(pv[mt][j] * inv) |
          ((unsigned int)f2b(pv[mt][j + 1] * inv) << 16);
      *(unsigned int*)&P_lds[qtok][mt * 16 + lg * 4 + j] = pk;
    }
  __syncthreads();

  const bf16x8 pa0 = *(const bf16x8*)&P_lds[qtok][lg * 8];
  const bf16x8 pa1 = *(const bf16x8*)&P_lds[qtok][32 + lg * 8];
  const unsigned short* vbase =
      XV + (size_t)lr * 131072 + (size_t)win * 64 + lg * 8;
  unsigned short* ybase[4];
#pragma unroll
  for (int r = 0; r < 4; ++r) {
    const int qq = qs + lg * 4 + r;
    ybase[r] =
        Y + (p_base + (size_t)(qq >> 3) * 128 + (qq & 7)) * 512 + lr;
  }
  bf16x8 v0p[2], v1p[2];
#pragma unroll
  for (int pp = 0; pp < 2; ++pp) {
    const unsigned short* vp = vbase + (size_t)pp * (16 * 131072);
    v0p[pp] = *(const bf16x8*)vp;
    v1p[pp] = *(const bf16x8*)(vp + 32);
  }
#pragma unroll
  for (int nt = 0; nt < 32; ++nt) {
    const int cb = nt & 1;
    bf16x8 v0n, v1n;
    if (nt + 2 < 32) {
      const unsigned short* vp = vbase + (size_t)(nt + 2) * (16 * 131072);
      v0n = *(const bf16x8*)vp;
      v1n = *(const bf16x8*)(vp + 32);
    }
    f32x4 o = f32x4{0.f, 0.f, 0.f, 0.f};
    __builtin_amdgcn_s_setprio(1);
    o = MFMA16(pa0, v0p[cb], o);
    o = MFMA16(pa1, v1p[cb], o);
    __builtin_amdgcn_s_setprio(0);
#pragma unroll
    for (int r = 0; r < 4; ++r) ybase[r][nt * 16] = f2b(o[r]);
    if (nt + 2 < 32) {
      v0p[cb] = v0n;
      v1p[cb] = v1n;
    }
  }
}

// ---------------- launch ----------------
extern "C" void kernel_launch(void* const* d_in, const int* in_sizes, int n_in,
                              void* d_out, int out_size, void* d_ws,
                              size_t ws_size, hipStream_t stream) {
  (void)in_sizes; (void)n_in; (void)out_size;
  const float* x = (const float*)d_in[0];
  const float* wq = (const float*)d_in[1];
  const float* bq = (const float*)d_in[2];
  const float* wk = (const float*)d_in[3];
  const float* bk = (const float*)d_in[4];  // cancels in softmax (exactly)
  const float* wv = (const float*)d_in[5];
  const float* bv = (const float*)d_in[6];
  const float* wo = (const float*)d_in[7];
  const float* bo = (const float*)d_in[8];
  (void)bk;

  const size_t NEED = (size_t)(2097152 + 3 * 67108864) * 2;
  if (ws_size < NEED) return;

  unsigned short* wb = (unsigned short*)d_ws;
  unsigned short* wqT = wb;
  unsigned short* wkT = wb + 262144;
  unsigned short* wvT = wb + 524288;
  unsigned short* wo_b = wb + 786432;
  unsigned short* wvo = wb + 1048576;
  float* bvo = (float*)(wb + 1310720);
  float* ub = (float*)(wb + 1311744);
  unsigned short* Bqk = wb + 1572864;
  unsigned short* xT = wb + 2097152;    // [pixel][c]
  unsigned short* xV = xT + 67108864;   // [c][win*64+tok]
  unsigned short* Ybuf = xV + 67108864; // attn output
  unsigned short* Tq = (unsigned short*)d_out;  // T staged (bf16), fully
                                                // overwritten by MODE 2 fp32

  k_wtrans<<<dim3(8, 8), 256, 0, stream>>>(wq, wqT);
  k_wtrans<<<dim3(8, 8), 256, 0, stream>>>(wk, wkT);
  k_wtrans<<<dim3(8, 8), 256, 0, stream>>>(wv, wvT);
  k_wconv<<<256, 256, 0, stream>>>(wo, wo_b);
  k_gemm256<3><<<4, 512, 0, stream>>>(wkT, wqT, nullptr, Bqk);   // Bqk[j][c]
  k_gemm256<3><<<4, 512, 0, stream>>>(wo_b, wvT, nullptr, wvo);  // Wvo = Wo*Wv
  k_ub<<<2, 256, 0, stream>>>(wk, bq, ub);
  k_bvo<<<2, 256, 0, stream>>>(wo, bv, bo, bvo);
  k_transpose<<<dim3(32, 16, 8), 256, 0, stream>>>(x, xT, xV);
  k_gemm256<0><<<1024, 512, 0, stream>>>(xT, Bqk, ub, Tq);       // T = X*Bqk^T + u
  k_attn<<<2048, 256, 0, stream>>>(Tq, xT, xV, Ybuf);
  k_gemm256<2><<<1024, 512, 0, stream>>>(wvo, Ybuf, bvo, d_out);
}

// Round 12
// 587.922 us; speedup vs baseline: 1.5742x; 1.0846x over previous
//
#include <hip/hip_runtime.h>

typedef __attribute__((ext_vector_type(8))) short bf16x8;
typedef __attribute__((ext_vector_type(4))) float f32x4;

#define MFMA16(a, b, c) __builtin_amdgcn_mfma_f32_16x16x32_bf16((a), (b), (c), 0, 0, 0)

__device__ __forceinline__ float b2f(unsigned short u) {
  unsigned int v = ((unsigned int)u) << 16;
  return __builtin_bit_cast(float, v);
}
__device__ __forceinline__ unsigned short f2b(float f) {
  unsigned int u = __builtin_bit_cast(unsigned int, f);
  u += 0x7fffu + ((u >> 16) & 1u);
  return (unsigned short)(u >> 16);
}
__device__ __forceinline__ void gload16(const void* g, void* l) {
  __builtin_amdgcn_global_load_lds(
      (const __attribute__((address_space(1))) unsigned int*)g,
      (__attribute__((address_space(3))) unsigned int*)l, 16, 0, 0);
}

// ---------------- wo fp32 -> bf16, layout preserved [o][c] ----------------
__global__ __launch_bounds__(256) void k_wconv(
    const float* __restrict__ src, unsigned short* __restrict__ dst) {
  const int i = (blockIdx.x * 256 + threadIdx.x) * 4;
  const float4 v = *(const float4*)(src + i);
  uint2 p;
  p.x = (unsigned int)f2b(v.x) | ((unsigned int)f2b(v.y) << 16);
  p.y = (unsigned int)f2b(v.z) | ((unsigned int)f2b(v.w) << 16);
  *(uint2*)(dst + i) = p;
}

// ---------------- w fp32 [a][b] -> bf16 [b][a] (512x512) ----------------
__global__ __launch_bounds__(256) void k_wtrans(
    const float* __restrict__ in, unsigned short* __restrict__ out) {
  __shared__ unsigned short tile[64][72];
  const int r0 = blockIdx.x << 6, s0 = blockIdx.y << 6;
  const int t = threadIdx.x;
  {
    const int sl = t >> 3, rl = (t & 7) << 3;
#pragma unroll
    for (int pass = 0; pass < 2; ++pass) {
      const int s = sl + pass * 32;
      const float* src = in + (size_t)(s0 + s) * 512 + r0 + rl;
      const float4 f0 = ((const float4*)src)[0];
      const float4 f1 = ((const float4*)src)[1];
      tile[rl + 0][s] = f2b(f0.x);
      tile[rl + 1][s] = f2b(f0.y);
      tile[rl + 2][s] = f2b(f0.z);
      tile[rl + 3][s] = f2b(f0.w);
      tile[rl + 4][s] = f2b(f1.x);
      tile[rl + 5][s] = f2b(f1.y);
      tile[rl + 6][s] = f2b(f1.z);
      tile[rl + 7][s] = f2b(f1.w);
    }
  }
  __syncthreads();
  {
    const int rl = t >> 3, sl = (t & 7) << 3;
#pragma unroll
    for (int pass = 0; pass < 2; ++pass) {
      const int r = rl + pass * 32;
      uint4 v = *(const uint4*)&tile[r][sl];
      *(uint4*)(out + (size_t)(r0 + r) * 512 + s0 + sl) = v;
    }
  }
}

// ---------------- bvo[o] = bo[o] + sum_j wo[o][j]*bv[j]  (fp32) ----------------
__global__ __launch_bounds__(256) void k_bvo(
    const float* __restrict__ wo, const float* __restrict__ bv,
    const float* __restrict__ bo, float* __restrict__ bvo) {
  const int o = blockIdx.x * 256 + threadIdx.x;
  float acc = bo[o];
  const float* row = wo + (size_t)o * 512;
  for (int j = 0; j < 512; ++j) acc += row[j] * bv[j];
  bvo[o] = acc;
}

// ---------------- u[c] = sum_o bq[o]*wk[o][c]  (fp32) ----------------
__global__ __launch_bounds__(256) void k_ub(
    const float* __restrict__ wk, const float* __restrict__ bq,
    float* __restrict__ u) {
  const int c = blockIdx.x * 256 + threadIdx.x;
  float acc = 0.f;
  for (int o = 0; o < 512; ++o) acc += bq[o] * wk[(size_t)o * 512 + c];
  u[c] = acc;
}

// ---- K0: x fp32 [b][c][h*128+w] -> xT bf16 [pixel][c] AND xV bf16 [c][win*64+tok] ----
__global__ __launch_bounds__(256) void k_transpose(
    const float* __restrict__ X, unsigned short* __restrict__ XT,
    unsigned short* __restrict__ XV) {
  __shared__ unsigned short tile[32][528];
  const int bx = blockIdx.x;
  const int wt = bx & 1, ht = bx >> 1;
  const int c0 = blockIdx.y << 5;
  const int b = blockIdx.z;
  const int w0 = wt << 6, h0 = ht << 3;
  const int t = threadIdx.x;
  const int cl = t >> 3, wl = t & 7;

  const float* xsrc = X + (size_t)b * 8388608u + (size_t)(c0 + cl) * 16384 +
                      (size_t)h0 * 128 + w0 + wl * 8;
  const int winb = b * 256 + ht * 16 + wt * 8;
  unsigned short* xvdst =
      XV + (size_t)(c0 + cl) * 131072 + (size_t)(winb + wl) * 64;

#pragma unroll
  for (int hh = 0; hh < 8; ++hh) {
    const float4 f0 = ((const float4*)(xsrc + hh * 128))[0];
    const float4 f1 = ((const float4*)(xsrc + hh * 128))[1];
    unsigned short r8[8];
    r8[0] = f2b(f0.x); r8[1] = f2b(f0.y); r8[2] = f2b(f0.z); r8[3] = f2b(f0.w);
    r8[4] = f2b(f1.x); r8[5] = f2b(f1.y); r8[6] = f2b(f1.z); r8[7] = f2b(f1.w);
    *(uint4*)&tile[cl][hh * 64 + wl * 8] = *(const uint4*)r8;
    *(uint4*)(xvdst + hh * 8) = *(const uint4*)r8;
  }
  __syncthreads();

  unsigned short* xtb = XT + (size_t)b * 8388608u;
#pragma unroll
  for (int pp = 0; pp < 2; ++pp) {
    const int pl = t + pp * 256;
    const int hh = pl >> 6, ww = pl & 63;
    unsigned short buf[32];
#pragma unroll
    for (int c = 0; c < 32; ++c) buf[c] = tile[c][pl];
    unsigned short* dst =
        xtb + ((size_t)(h0 + hh) * 128 + w0 + ww) * 512 + c0;
    *(uint4*)(dst + 0) = *(const uint4*)&buf[0];
    *(uint4*)(dst + 8) = *(const uint4*)&buf[8];
    *(uint4*)(dst + 16) = *(const uint4*)&buf[16];
    *(uint4*)(dst + 24) = *(const uint4*)&buf[24];
  }
}

// ========== 256x256 GEMM, K=512 as 16 K-subtiles of 32, depth-3 counted pipeline ==========
template <int MODE>
__global__ __launch_bounds__(512, 2) void k_gemm256(
    const unsigned short* __restrict__ A, const unsigned short* __restrict__ B,
    const float* __restrict__ bias0, void* __restrict__ C0v) {
  __shared__ unsigned short lsA[4][256 * 32];
  __shared__ unsigned short lsB[4][256 * 32];
  const int bid = blockIdx.x;
  int mt, nt;
  if (MODE == 0) {
    const int work = ((bid & 7) << 7) + (bid >> 3);  // grid 1024
    mt = work >> 1; nt = work & 1;
  } else if (MODE == 2) {
    const int work = ((bid & 7) << 7) + (bid >> 3);  // grid 1024
    nt = work >> 1; mt = work & 1;
  } else {
    mt = bid & 1; nt = bid >> 1;                     // grid 4
  }
  const int m0 = mt << 8, n0 = nt << 8;

  const int t = threadIdx.x;
  const int l = t & 63;
  const int lr = l & 15, lg = l >> 4;
  const int w = t >> 6;
  const int wr = w >> 2, wc = w & 3;
  const int ra = wr << 7, rb = wc << 6;
  const int srowS = t >> 2;
  const int scolS = (t & 3) << 3;

  f32x4 acc[8][4];
#pragma unroll
  for (int i = 0; i < 8; ++i)
#pragma unroll
    for (int j = 0; j < 4; ++j) acc[i][j] = f32x4{0.f, 0.f, 0.f, 0.f};

  auto stage = [&](int kt) {
    const int buf = kt & 3, k0 = kt << 5;
#pragma unroll
    for (int hh = 0; hh < 2; ++hh) {
      gload16(A + (size_t)(m0 + srowS + hh * 128) * 512 + k0 + scolS,
              &lsA[buf][(srowS + hh * 128) * 32 + scolS]);
      gload16(B + (size_t)(n0 + srowS + hh * 128) * 512 + k0 + scolS,
              &lsB[buf][(srowS + hh * 128) * 32 + scolS]);
    }
  };
  auto compute = [&](int kt) {
    const int buf = kt & 3;
    bf16x8 af[8], bfv[4];
#pragma unroll
    for (int i = 0; i < 8; ++i)
      af[i] = *(const bf16x8*)&lsA[buf][(ra + i * 16 + lr) * 32 + lg * 8];
#pragma unroll
    for (int j = 0; j < 4; ++j)
      bfv[j] = *(const bf16x8*)&lsB[buf][(rb + j * 16 + lr) * 32 + lg * 8];
    __builtin_amdgcn_s_setprio(1);
#pragma unroll
    for (int i = 0; i < 8; ++i)
#pragma unroll
      for (int j = 0; j < 4; ++j)
        acc[i][j] = MFMA16(af[i], bfv[j], acc[i][j]);
    __builtin_amdgcn_s_setprio(0);
  };

  stage(0); stage(1); stage(2);

#define GITER(kt, vm)                                        \
  asm volatile("s_waitcnt vmcnt(" #vm ")" ::: "memory");     \
  __builtin_amdgcn_s_barrier();                              \
  __builtin_amdgcn_sched_barrier(0);                         \
  if ((kt) + 3 < 16) stage((kt) + 3);                        \
  compute(kt);                                               \
  __builtin_amdgcn_sched_barrier(0);                         \
  __builtin_amdgcn_s_barrier();

  GITER(0, 8)  GITER(1, 8)  GITER(2, 8)  GITER(3, 8)
  GITER(4, 8)  GITER(5, 8)  GITER(6, 8)  GITER(7, 8)
  GITER(8, 8)  GITER(9, 8)  GITER(10, 8) GITER(11, 8)
  GITER(12, 8) GITER(13, 8) GITER(14, 4) GITER(15, 0)
#undef GITER

#pragma unroll
  for (int i = 0; i < 8; ++i) {
    const int cmb = m0 + ra + i * 16 + lg * 4;
#pragma unroll
    for (int j = 0; j < 4; ++j) {
      const int cn = n0 + rb + j * 16 + lr;
      const float bn = (MODE == 0) ? bias0[cn] : 0.f;
#pragma unroll
      for (int r = 0; r < 4; ++r) {
        const int cm = cmb + r;
        if (MODE == 0) {
          ((unsigned short*)C0v)[(size_t)cm * 512 + cn] = f2b(acc[i][j][r] + bn);
        } else if (MODE == 2) {
          const float val = acc[i][j][r] + bias0[cm];
          const int bb = cn >> 14, p = cn & 16383;
          ((float*)C0v)[(size_t)bb * 8388608 + (size_t)cm * 16384 + p] = val;
        } else {
          ((unsigned short*)C0v)[(size_t)cm * 512 + cn] = f2b(acc[i][j][r]);
        }
      }
    }
  }
}

// ---------------- K2: window attention, ONE WAVE PER WINDOW ----------------
// Q(=T): [pixel][c] bf16.  XT: [pixel][c] bf16 (K-side).  XV: [c][win*64+tok] bf16.
// Y out: [pixel][c] bf16.  Block = 4 windows (4 waves); no block barriers.
__global__ __launch_bounds__(256) void k_attn(
    const unsigned short* __restrict__ Q, const unsigned short* __restrict__ XT,
    const unsigned short* __restrict__ XV, unsigned short* __restrict__ Y) {
  __shared__ unsigned short P_lds[4][64][72];
  const int t = threadIdx.x, w = t >> 6, l = t & 63;
  const int lr = l & 15, lg = l >> 4;
  const int grp = ((blockIdx.x & 7) << 6) + (blockIdx.x >> 3);  // 0..511
  const int win = grp * 4 + w;
  const int b = win >> 8, th = (win >> 4) & 15, tw = win & 15;
  const size_t p_base = (size_t)b * 16384 + (size_t)th * 1024 + (size_t)tw * 8;
  const size_t rowpix = p_base + (size_t)(lr >> 3) * 128 + (lr & 7);
  const unsigned short* qbase = Q + rowpix * 512;   // B-op: tokens qt*16+lr
  const unsigned short* kbase = XT + rowpix * 512;  // A-op: tokens mt*16+lr

  // S'[k][q] = mfma(A=K, B=Q): acc[mt][qt]; lane: q=qt*16+lr, k=mt*16+lg*4+j
  f32x4 acc[4][4];
#pragma unroll
  for (int i = 0; i < 4; ++i)
#pragma unroll
    for (int j = 0; j < 4; ++j) acc[i][j] = f32x4{0.f, 0.f, 0.f, 0.f};

  bf16x8 kp[2][4], qp[2][4];
#pragma unroll
  for (int pp = 0; pp < 2; ++pp) {
    const int co = pp * 32 + lg * 8;
#pragma unroll
    for (int i = 0; i < 4; ++i) {
      kp[pp][i] = *(const bf16x8*)(kbase + (size_t)i * 131072 + co);
      qp[pp][i] = *(const bf16x8*)(qbase + (size_t)i * 131072 + co);
    }
  }
#pragma unroll
  for (int cs = 0; cs < 16; ++cs) {
    const int cb = cs & 1;
    __builtin_amdgcn_s_setprio(1);
#pragma unroll
    for (int mt = 0; mt < 4; ++mt)
#pragma unroll
      for (int qt = 0; qt < 4; ++qt)
        acc[mt][qt] = MFMA16(kp[cb][mt], qp[cb][qt], acc[mt][qt]);
    __builtin_amdgcn_s_setprio(0);
    if (cs + 2 < 16) {
      const int co = (cs + 2) * 32 + lg * 8;
#pragma unroll
      for (int i = 0; i < 4; ++i) {
        kp[cb][i] = *(const bf16x8*)(kbase + (size_t)i * 131072 + co);
        qp[cb][i] = *(const bf16x8*)(qbase + (size_t)i * 131072 + co);
      }
    }
  }

  // per-qt in-register softmax; P -> per-wave LDS slice (no block barrier)
  const float scale = 0.044194173824159216f;  // 1/sqrt(512)
#pragma unroll
  for (int qt = 0; qt < 4; ++qt) {
    float pv[4][4];
    float mx = -3.0e38f;
#pragma unroll
    for (int mt = 0; mt < 4; ++mt)
#pragma unroll
      for (int j = 0; j < 4; ++j) {
        const float s = acc[mt][qt][j] * scale;
        pv[mt][j] = s;
        mx = fmaxf(mx, s);
      }
    mx = fmaxf(mx, __shfl_xor(mx, 16));
    mx = fmaxf(mx, __shfl_xor(mx, 32));
    float sum = 0.f;
#pragma unroll
    for (int mt = 0; mt < 4; ++mt)
#pragma unroll
      for (int j = 0; j < 4; ++j) {
        const float e = __expf(pv[mt][j] - mx);
        pv[mt][j] = e;
        sum += e;
      }
    sum += __shfl_xor(sum, 16);
    sum += __shfl_xor(sum, 32);
    const float inv = 1.f / sum;
#pragma unroll
    for (int mt = 0; mt < 4; ++mt)
#pragma unroll
      for (int j = 0; j < 4; j += 2) {
        const unsigned int pk =
            (unsigned int)f2b(pv[mt][j] * inv) |
            ((unsigned int)f2b(pv[mt][j + 1] * inv) << 16);
        *(unsigned int*)&P_lds[w][qt * 16 + lr][mt * 16 + lg * 4 + j] = pk;
      }
  }

  // PV: Y[q][c] = mfma(A=P, B=V); V reused across 4 qt tiles per nt
  bf16x8 pa0[4], pa1[4];
#pragma unroll
  for (int qt = 0; qt < 4; ++qt) {
    pa0[qt] = *(const bf16x8*)&P_lds[w][qt * 16 + lr][lg * 8];
    pa1[qt] = *(const bf16x8*)&P_lds[w][qt * 16 + lr][32 + lg * 8];
  }
  const unsigned short* vbase =
      XV + (size_t)lr * 131072 + (size_t)win * 64 + lg * 8;
  unsigned short* ystore =
      Y + (p_base + (size_t)(lg >> 1) * 128 + ((lg & 1) << 2)) * 512 + lr;

  bf16x8 v0p[2], v1p[2];
#pragma unroll
  for (int pp = 0; pp < 2; ++pp) {
    const unsigned short* vp = vbase + (size_t)pp * (16 * 131072);
    v0p[pp] = *(const bf16x8*)vp;
    v1p[pp] = *(const bf16x8*)(vp + 32);
  }
#pragma unroll
  for (int nt = 0; nt < 32; ++nt) {
    const int cb = nt & 1;
    f32x4 o[4];
    __builtin_amdgcn_s_setprio(1);
#pragma unroll
    for (int qt = 0; qt < 4; ++qt) {
      o[qt] = f32x4{0.f, 0.f, 0.f, 0.f};
      o[qt] = MFMA16(pa0[qt], v0p[cb], o[qt]);
      o[qt] = MFMA16(pa1[qt], v1p[cb], o[qt]);
    }
    __builtin_amdgcn_s_setprio(0);
    if (nt + 2 < 32) {
      const unsigned short* vp = vbase + (size_t)(nt + 2) * (16 * 131072);
      v0p[cb] = *(const bf16x8*)vp;
      v1p[cb] = *(const bf16x8*)(vp + 32);
    }
#pragma unroll
    for (int qt = 0; qt < 4; ++qt)
#pragma unroll
      for (int r = 0; r < 4; ++r)
        ystore[(size_t)qt * 131072 + r * 512 + nt * 16] = f2b(o[qt][r]);
  }
}

// ---------------- launch ----------------
extern "C" void kernel_launch(void* const* d_in, const int* in_sizes, int n_in,
                              void* d_out, int out_size, void* d_ws,
                              size_t ws_size, hipStream_t stream) {
  (void)in_sizes; (void)n_in; (void)out_size;
  const float* x = (const float*)d_in[0];
  const float* wq = (const float*)d_in[1];
  const float* bq = (const float*)d_in[2];
  const float* wk = (const float*)d_in[3];
  const float* bk = (const float*)d_in[4];  // cancels in softmax (exactly)
  const float* wv = (const float*)d_in[5];
  const float* bv = (const float*)d_in[6];
  const float* wo = (const float*)d_in[7];
  const float* bo = (const float*)d_in[8];
  (void)bk;

  const size_t NEED = (size_t)(2097152 + 3 * 67108864) * 2;
  if (ws_size < NEED) return;

  unsigned short* wb = (unsigned short*)d_ws;
  unsigned short* wqT = wb;
  unsigned short* wkT = wb + 262144;
  unsigned short* wvT = wb + 524288;
  unsigned short* wo_b = wb + 786432;
  unsigned short* wvo = wb + 1048576;
  float* bvo = (float*)(wb + 1310720);
  float* ub = (float*)(wb + 1311744);
  unsigned short* Bqk = wb + 1572864;
  unsigned short* xT = wb + 2097152;    // [pixel][c]
  unsigned short* xV = xT + 67108864;   // [c][win*64+tok]
  unsigned short* Ybuf = xV + 67108864; // attn output
  unsigned short* Tq = (unsigned short*)d_out;  // T staged (bf16), fully
                                                // overwritten by MODE 2 fp32

  k_wtrans<<<dim3(8, 8), 256, 0, stream>>>(wq, wqT);
  k_wtrans<<<dim3(8, 8), 256, 0, stream>>>(wk, wkT);
  k_wtrans<<<dim3(8, 8), 256, 0, stream>>>(wv, wvT);
  k_wconv<<<256, 256, 0, stream>>>(wo, wo_b);
  k_gemm256<3><<<4, 512, 0, stream>>>(wkT, wqT, nullptr, Bqk);   // Bqk[j][c]
  k_gemm256<3><<<4, 512, 0, stream>>>(wo_b, wvT, nullptr, wvo);  // Wvo = Wo*Wv
  k_ub<<<2, 256, 0, stream>>>(wk, bq, ub);
  k_bvo<<<2, 256, 0, stream>>>(wo, bv, bo, bvo);
  k_transpose<<<dim3(32, 16, 8), 256, 0, stream>>>(x, xT, xV);
  k_gemm256<0><<<1024, 512, 0, stream>>>(xT, Bqk, ub, Tq);       // T = X*Bqk^T + u
  k_attn<<<512, 256, 0, stream>>>(Tq, xT, xV, Ybuf);
  k_gemm256<2><<<1024, 512, 0, stream>>>(wvo, Ybuf, bvo, d_out);
}

// Round 13
// 583.542 us; speedup vs baseline: 1.5860x; 1.0075x over previous
//
#include <hip/hip_runtime.h>

typedef __attribute__((ext_vector_type(8))) short bf16x8;
typedef __attribute__((ext_vector_type(4))) float f32x4;

#define MFMA16(a, b, c) __builtin_amdgcn_mfma_f32_16x16x32_bf16((a), (b), (c), 0, 0, 0)

__device__ __forceinline__ float b2f(unsigned short u) {
  unsigned int v = ((unsigned int)u) << 16;
  return __builtin_bit_cast(float, v);
}
__device__ __forceinline__ unsigned short f2b(float f) {
  unsigned int u = __builtin_bit_cast(unsigned int, f);
  u += 0x7fffu + ((u >> 16) & 1u);
  return (unsigned short)(u >> 16);
}
__device__ __forceinline__ void gload16(const void* g, void* l) {
  __builtin_amdgcn_global_load_lds(
      (const __attribute__((address_space(1))) unsigned int*)g,
      (__attribute__((address_space(3))) unsigned int*)l, 16, 0, 0);
}

// ---------------- wo fp32 -> bf16, layout preserved [o][c] ----------------
__global__ __launch_bounds__(256) void k_wconv(
    const float* __restrict__ src, unsigned short* __restrict__ dst) {
  const int i = (blockIdx.x * 256 + threadIdx.x) * 4;
  const float4 v = *(const float4*)(src + i);
  uint2 p;
  p.x = (unsigned int)f2b(v.x) | ((unsigned int)f2b(v.y) << 16);
  p.y = (unsigned int)f2b(v.z) | ((unsigned int)f2b(v.w) << 16);
  *(uint2*)(dst + i) = p;
}

// ---------------- w fp32 [a][b] -> bf16 [b][a] (512x512) ----------------
__global__ __launch_bounds__(256) void k_wtrans(
    const float* __restrict__ in, unsigned short* __restrict__ out) {
  __shared__ unsigned short tile[64][72];
  const int r0 = blockIdx.x << 6, s0 = blockIdx.y << 6;
  const int t = threadIdx.x;
  {
    const int sl = t >> 3, rl = (t & 7) << 3;
#pragma unroll
    for (int pass = 0; pass < 2; ++pass) {
      const int s = sl + pass * 32;
      const float* src = in + (size_t)(s0 + s) * 512 + r0 + rl;
      const float4 f0 = ((const float4*)src)[0];
      const float4 f1 = ((const float4*)src)[1];
      tile[rl + 0][s] = f2b(f0.x);
      tile[rl + 1][s] = f2b(f0.y);
      tile[rl + 2][s] = f2b(f0.z);
      tile[rl + 3][s] = f2b(f0.w);
      tile[rl + 4][s] = f2b(f1.x);
      tile[rl + 5][s] = f2b(f1.y);
      tile[rl + 6][s] = f2b(f1.z);
      tile[rl + 7][s] = f2b(f1.w);
    }
  }
  __syncthreads();
  {
    const int rl = t >> 3, sl = (t & 7) << 3;
#pragma unroll
    for (int pass = 0; pass < 2; ++pass) {
      const int r = rl + pass * 32;
      uint4 v = *(const uint4*)&tile[r][sl];
      *(uint4*)(out + (size_t)(r0 + r) * 512 + s0 + sl) = v;
    }
  }
}

// ---------------- bvo[o] = bo[o] + sum_j wo[o][j]*bv[j]  (fp32) ----------------
__global__ __launch_bounds__(256) void k_bvo(
    const float* __restrict__ wo, const float* __restrict__ bv,
    const float* __restrict__ bo, float* __restrict__ bvo) {
  const int o = blockIdx.x * 256 + threadIdx.x;
  float acc = bo[o];
  const float* row = wo + (size_t)o * 512;
  for (int j = 0; j < 512; ++j) acc += row[j] * bv[j];
  bvo[o] = acc;
}

// ---------------- u[c] = sum_o bq[o]*wk[o][c]  (fp32) ----------------
__global__ __launch_bounds__(256) void k_ub(
    const float* __restrict__ wk, const float* __restrict__ bq,
    float* __restrict__ u) {
  const int c = blockIdx.x * 256 + threadIdx.x;
  float acc = 0.f;
  for (int o = 0; o < 512; ++o) acc += bq[o] * wk[(size_t)o * 512 + c];
  u[c] = acc;
}

// ---- K0: LDS-free transpose. x fp32 [b][c][h*128+w] -> xT bf16 [pixel][c]
//      AND xV bf16 [c][win*64+tok]. Thread owns an 8px(window-row) x 8ch block;
//      the 8x8 transpose is pure register pack order. Lane map t=(wi*8+hh)*4+cg
//      gives full-line coverage for reads, xT stores, and xV stores.
__global__ __launch_bounds__(256) void k_transpose(
    const float* __restrict__ X, unsigned short* __restrict__ XT,
    unsigned short* __restrict__ XV) {
  const int bx = blockIdx.x;            // 0..31
  const int wt = bx & 1, ht = bx >> 1;
  const int c0 = blockIdx.y << 5;
  const int b = blockIdx.z;
  const int w0 = wt << 6, h0 = ht << 3;
  const int t = threadIdx.x;
  const int cg = t & 3, pg = t >> 2;
  const int wi = pg >> 3, hh = pg & 7;  // w-major: wave covers hh=0..7 of 2 wins
  const int h = h0 + hh, w = w0 + wi * 8;
  const int cbase = c0 + cg * 8;

  const float* xsrc = X + (size_t)b * 8388608u + (size_t)cbase * 16384 +
                      (size_t)h * 128 + w;
  float f[8][8];
#pragma unroll
  for (int ci = 0; ci < 8; ++ci) {
    const float4 a0 = ((const float4*)(xsrc + (size_t)ci * 16384))[0];
    const float4 a1 = ((const float4*)(xsrc + (size_t)ci * 16384))[1];
    f[ci][0] = a0.x; f[ci][1] = a0.y; f[ci][2] = a0.z; f[ci][3] = a0.w;
    f[ci][4] = a1.x; f[ci][5] = a1.y; f[ci][6] = a1.z; f[ci][7] = a1.w;
  }

  // xT: pixel-major 16B vectors (4 cg-lanes complete each 64B line)
  unsigned short* xtdst =
      XT + (size_t)b * 8388608u + ((size_t)h * 128 + w) * 512 + cbase;
#pragma unroll
  for (int pi = 0; pi < 8; ++pi) {
    unsigned short o[8];
#pragma unroll
    for (int ci = 0; ci < 8; ++ci) o[ci] = f2b(f[ci][pi]);
    *(uint4*)(xtdst + (size_t)pi * 512) = *(const uint4*)o;
  }

  // xV: channel-major 16B vectors (hh=0..7 lanes complete each 128B region)
  const int win = b * 256 + ht * 16 + wt * 8 + wi;
  unsigned short* xvdst =
      XV + (size_t)cbase * 131072 + (size_t)win * 64 + hh * 8;
#pragma unroll
  for (int ci = 0; ci < 8; ++ci) {
    unsigned short o[8];
#pragma unroll
    for (int pi = 0; pi < 8; ++pi) o[pi] = f2b(f[ci][pi]);
    *(uint4*)(xvdst + (size_t)ci * 131072) = *(const uint4*)o;
  }
}

// ========== 256x256 GEMM, K=512 as 16 K-subtiles of 32, depth-3 counted pipeline ==========
template <int MODE>
__global__ __launch_bounds__(512, 2) void k_gemm256(
    const unsigned short* __restrict__ A, const unsigned short* __restrict__ B,
    const float* __restrict__ bias0, void* __restrict__ C0v) {
  __shared__ unsigned short lsA[4][256 * 32];
  __shared__ unsigned short lsB[4][256 * 32];
  const int bid = blockIdx.x;
  int mt, nt;
  if (MODE == 0) {
    const int work = ((bid & 7) << 7) + (bid >> 3);  // grid 1024
    mt = work >> 1; nt = work & 1;
  } else if (MODE == 2) {
    const int work = ((bid & 7) << 7) + (bid >> 3);  // grid 1024
    nt = work >> 1; mt = work & 1;
  } else {
    mt = bid & 1; nt = bid >> 1;                     // grid 4
  }
  const int m0 = mt << 8, n0 = nt << 8;

  const int t = threadIdx.x;
  const int l = t & 63;
  const int lr = l & 15, lg = l >> 4;
  const int w = t >> 6;
  const int wr = w >> 2, wc = w & 3;
  const int ra = wr << 7, rb = wc << 6;
  const int srowS = t >> 2;
  const int scolS = (t & 3) << 3;

  f32x4 acc[8][4];
#pragma unroll
  for (int i = 0; i < 8; ++i)
#pragma unroll
    for (int j = 0; j < 4; ++j) acc[i][j] = f32x4{0.f, 0.f, 0.f, 0.f};

  auto stage = [&](int kt) {
    const int buf = kt & 3, k0 = kt << 5;
#pragma unroll
    for (int hh = 0; hh < 2; ++hh) {
      gload16(A + (size_t)(m0 + srowS + hh * 128) * 512 + k0 + scolS,
              &lsA[buf][(srowS + hh * 128) * 32 + scolS]);
      gload16(B + (size_t)(n0 + srowS + hh * 128) * 512 + k0 + scolS,
              &lsB[buf][(srowS + hh * 128) * 32 + scolS]);
    }
  };
  auto compute = [&](int kt) {
    const int buf = kt & 3;
    bf16x8 af[8], bfv[4];
#pragma unroll
    for (int i = 0; i < 8; ++i)
      af[i] = *(const bf16x8*)&lsA[buf][(ra + i * 16 + lr) * 32 + lg * 8];
#pragma unroll
    for (int j = 0; j < 4; ++j)
      bfv[j] = *(const bf16x8*)&lsB[buf][(rb + j * 16 + lr) * 32 + lg * 8];
    __builtin_amdgcn_s_setprio(1);
#pragma unroll
    for (int i = 0; i < 8; ++i)
#pragma unroll
      for (int j = 0; j < 4; ++j)
        acc[i][j] = MFMA16(af[i], bfv[j], acc[i][j]);
    __builtin_amdgcn_s_setprio(0);
  };

  stage(0); stage(1); stage(2);

#define GITER(kt, vm)                                        \
  asm volatile("s_waitcnt vmcnt(" #vm ")" ::: "memory");     \
  __builtin_amdgcn_s_barrier();                              \
  __builtin_amdgcn_sched_barrier(0);                         \
  if ((kt) + 3 < 16) stage((kt) + 3);                        \
  compute(kt);                                               \
  __builtin_amdgcn_sched_barrier(0);                         \
  __builtin_amdgcn_s_barrier();

  GITER(0, 8)  GITER(1, 8)  GITER(2, 8)  GITER(3, 8)
  GITER(4, 8)  GITER(5, 8)  GITER(6, 8)  GITER(7, 8)
  GITER(8, 8)  GITER(9, 8)  GITER(10, 8) GITER(11, 8)
  GITER(12, 8) GITER(13, 8) GITER(14, 4) GITER(15, 0)
#undef GITER

#pragma unroll
  for (int i = 0; i < 8; ++i) {
    const int cmb = m0 + ra + i * 16 + lg * 4;
#pragma unroll
    for (int j = 0; j < 4; ++j) {
      const int cn = n0 + rb + j * 16 + lr;
      const float bn = (MODE == 0) ? bias0[cn] : 0.f;
#pragma unroll
      for (int r = 0; r < 4; ++r) {
        const int cm = cmb + r;
        if (MODE == 0) {
          ((unsigned short*)C0v)[(size_t)cm * 512 + cn] = f2b(acc[i][j][r] + bn);
        } else if (MODE == 2) {
          const float val = acc[i][j][r] + bias0[cm];
          const int bb = cn >> 14, p = cn & 16383;
          ((float*)C0v)[(size_t)bb * 8388608 + (size_t)cm * 16384 + p] = val;
        } else {
          ((unsigned short*)C0v)[(size_t)cm * 512 + cn] = f2b(acc[i][j][r]);
        }
      }
    }
  }
}

// ---------------- K2: window attention, ONE WAVE PER WINDOW ----------------
__global__ __launch_bounds__(256) void k_attn(
    const unsigned short* __restrict__ Q, const unsigned short* __restrict__ XT,
    const unsigned short* __restrict__ XV, unsigned short* __restrict__ Y) {
  __shared__ unsigned short P_lds[4][64][72];
  const int t = threadIdx.x, w = t >> 6, l = t & 63;
  const int lr = l & 15, lg = l >> 4;
  const int grp = ((blockIdx.x & 7) << 6) + (blockIdx.x >> 3);  // 0..511
  const int win = grp * 4 + w;
  const int b = win >> 8, th = (win >> 4) & 15, tw = win & 15;
  const size_t p_base = (size_t)b * 16384 + (size_t)th * 1024 + (size_t)tw * 8;
  const size_t rowpix = p_base + (size_t)(lr >> 3) * 128 + (lr & 7);
  const unsigned short* qbase = Q + rowpix * 512;
  const unsigned short* kbase = XT + rowpix * 512;

  f32x4 acc[4][4];
#pragma unroll
  for (int i = 0; i < 4; ++i)
#pragma unroll
    for (int j = 0; j < 4; ++j) acc[i][j] = f32x4{0.f, 0.f, 0.f, 0.f};

  bf16x8 kp[2][4], qp[2][4];
#pragma unroll
  for (int pp = 0; pp < 2; ++pp) {
    const int co = pp * 32 + lg * 8;
#pragma unroll
    for (int i = 0; i < 4; ++i) {
      kp[pp][i] = *(const bf16x8*)(kbase + (size_t)i * 131072 + co);
      qp[pp][i] = *(const bf16x8*)(qbase + (size_t)i * 131072 + co);
    }
  }
#pragma unroll
  for (int cs = 0; cs < 16; ++cs) {
    const int cb = cs & 1;
    __builtin_amdgcn_s_setprio(1);
#pragma unroll
    for (int mt = 0; mt < 4; ++mt)
#pragma unroll
      for (int qt = 0; qt < 4; ++qt)
        acc[mt][qt] = MFMA16(kp[cb][mt], qp[cb][qt], acc[mt][qt]);
    __builtin_amdgcn_s_setprio(0);
    if (cs + 2 < 16) {
      const int co = (cs + 2) * 32 + lg * 8;
#pragma unroll
      for (int i = 0; i < 4; ++i) {
        kp[cb][i] = *(const bf16x8*)(kbase + (size_t)i * 131072 + co);
        qp[cb][i] = *(const bf16x8*)(qbase + (size_t)i * 131072 + co);
      }
    }
  }

  const float scale = 0.044194173824159216f;  // 1/sqrt(512)
#pragma unroll
  for (int qt = 0; qt < 4; ++qt) {
    float pv[4][4];
    float mx = -3.0e38f;
#pragma unroll
    for (int mt = 0; mt < 4; ++mt)
#pragma unroll
      for (int j = 0; j < 4; ++j) {
        const float s = acc[mt][qt][j] * scale;
        pv[mt][j] = s;
        mx = fmaxf(mx, s);
      }
    mx = fmaxf(mx, __shfl_xor(mx, 16));
    mx = fmaxf(mx, __shfl_xor(mx, 32));
    float sum = 0.f;
#pragma unroll
    for (int mt = 0; mt < 4; ++mt)
#pragma unroll
      for (int j = 0; j < 4; ++j) {
        const float e = __expf(pv[mt][j] - mx);
        pv[mt][j] = e;
        sum += e;
      }
    sum += __shfl_xor(sum, 16);
    sum += __shfl_xor(sum, 32);
    const float inv = 1.f / sum;
#pragma unroll
    for (int mt = 0; mt < 4; ++mt)
#pragma unroll
      for (int j = 0; j < 4; j += 2) {
        const unsigned int pk =
            (unsigned int)f2b(pv[mt][j] * inv) |
            ((unsigned int)f2b(pv[mt][j + 1] * inv) << 16);
        *(unsigned int*)&P_lds[w][qt * 16 + lr][mt * 16 + lg * 4 + j] = pk;
      }
  }

  bf16x8 pa0[4], pa1[4];
#pragma unroll
  for (int qt = 0; qt < 4; ++qt) {
    pa0[qt] = *(const bf16x8*)&P_lds[w][qt * 16 + lr][lg * 8];
    pa1[qt] = *(const bf16x8*)&P_lds[w][qt * 16 + lr][32 + lg * 8];
  }
  const unsigned short* vbase =
      XV + (size_t)lr * 131072 + (size_t)win * 64 + lg * 8;
  unsigned short* ystore =
      Y + (p_base + (size_t)(lg >> 1) * 128 + ((lg & 1) << 2)) * 512 + lr;

  bf16x8 v0p[2], v1p[2];
#pragma unroll
  for (int pp = 0; pp < 2; ++pp) {
    const unsigned short* vp = vbase + (size_t)pp * (16 * 131072);
    v0p[pp] = *(const bf16x8*)vp;
    v1p[pp] = *(const bf16x8*)(vp + 32);
  }
#pragma unroll
  for (int nt = 0; nt < 32; ++nt) {
    const int cb = nt & 1;
    f32x4 o[4];
    __builtin_amdgcn_s_setprio(1);
#pragma unroll
    for (int qt = 0; qt < 4; ++qt) {
      o[qt] = f32x4{0.f, 0.f, 0.f, 0.f};
      o[qt] = MFMA16(pa0[qt], v0p[cb], o[qt]);
      o[qt] = MFMA16(pa1[qt], v1p[cb], o[qt]);
    }
    __builtin_amdgcn_s_setprio(0);
    if (nt + 2 < 32) {
      const unsigned short* vp = vbase + (size_t)(nt + 2) * (16 * 131072);
      v0p[cb] = *(const bf16x8*)vp;
      v1p[cb] = *(const bf16x8*)(vp + 32);
    }
#pragma unroll
    for (int qt = 0; qt < 4; ++qt)
#pragma unroll
      for (int r = 0; r < 4; ++r)
        ystore[(size_t)qt * 131072 + r * 512 + nt * 16] = f2b(o[qt][r]);
  }
}

// ---------------- launch ----------------
extern "C" void kernel_launch(void* const* d_in, const int* in_sizes, int n_in,
                              void* d_out, int out_size, void* d_ws,
                              size_t ws_size, hipStream_t stream) {
  (void)in_sizes; (void)n_in; (void)out_size;
  const float* x = (const float*)d_in[0];
  const float* wq = (const float*)d_in[1];
  const float* bq = (const float*)d_in[2];
  const float* wk = (const float*)d_in[3];
  const float* bk = (const float*)d_in[4];  // cancels in softmax (exactly)
  const float* wv = (const float*)d_in[5];
  const float* bv = (const float*)d_in[6];
  const float* wo = (const float*)d_in[7];
  const float* bo = (const float*)d_in[8];
  (void)bk;

  const size_t NEED = (size_t)(2097152 + 3 * 67108864) * 2;
  if (ws_size < NEED) return;

  unsigned short* wb = (unsigned short*)d_ws;
  unsigned short* wqT = wb;
  unsigned short* wkT = wb + 262144;
  unsigned short* wvT = wb + 524288;
  unsigned short* wo_b = wb + 786432;
  unsigned short* wvo = wb + 1048576;
  float* bvo = (float*)(wb + 1310720);
  float* ub = (float*)(wb + 1311744);
  unsigned short* Bqk = wb + 1572864;
  unsigned short* xT = wb + 2097152;    // [pixel][c]
  unsigned short* xV = xT + 67108864;   // [c][win*64+tok]
  unsigned short* Ybuf = xV + 67108864; // attn output
  unsigned short* Tq = (unsigned short*)d_out;  // T staged (bf16), fully
                                                // overwritten by MODE 2 fp32

  k_wtrans<<<dim3(8, 8), 256, 0, stream>>>(wq, wqT);
  k_wtrans<<<dim3(8, 8), 256, 0, stream>>>(wk, wkT);
  k_wtrans<<<dim3(8, 8), 256, 0, stream>>>(wv, wvT);
  k_wconv<<<256, 256, 0, stream>>>(wo, wo_b);
  k_gemm256<3><<<4, 512, 0, stream>>>(wkT, wqT, nullptr, Bqk);   // Bqk[j][c]
  k_gemm256<3><<<4, 512, 0, stream>>>(wo_b, wvT, nullptr, wvo);  // Wvo = Wo*Wv
  k_ub<<<2, 256, 0, stream>>>(wk, bq, ub);
  k_bvo<<<2, 256, 0, stream>>>(wo, bv, bo, bvo);
  k_transpose<<<dim3(32, 16, 8), 256, 0, stream>>>(x, xT, xV);
  k_gemm256<0><<<1024, 512, 0, stream>>>(xT, Bqk, ub, Tq);       // T = X*Bqk^T + u
  k_attn<<<512, 256, 0, stream>>>(Tq, xT, xV, Ybuf);
  k_gemm256<2><<<1024, 512, 0, stream>>>(wvo, Ybuf, bvo, d_out);
}